// Round 10
// baseline (1295.797 us; speedup 1.0000x reference)
//
#include <hip/hip_runtime.h>
#include <hip/hip_bf16.h>
#include <math.h>

// TransformerBlock3D: B=8, C=128, S=32 (N=32768), HEADS=8 (dim_head=16), MLP=512
// Round 14: R13 retry without the register cap. R13's regression was VGPR=64
// (launch_bounds(512,4) -> 128-combined cap vs ~144 needed -> per-os spills to
// scratch; dur x MfmaUtil still ~2800). Occupancy lever itself not falsified.
//  - k_mlp/k_attnproj: launch_bounds(512,2) (cap 256, no spills).
//  - k_mlp staging: 2 batches of 2 rows (lower peak reg pressure; staging
//    fetch-volume proven non-critical in R10).
// Math: G=XX^T, attn=softmax(0.25*WqGWk^T), Mb=P.blockdiag(attn).Wv (bf16),
//       x1pre = Mb x + proj_b + x; x1 = LN1(x1pre); x2pre = x1 + b2 + W2 gelu(W1 x1 + b1).

#define N_SP 32768
typedef __hip_bfloat16 bf16;
static const size_t DS = (size_t)128 * N_SP;

typedef __attribute__((ext_vector_type(8))) short s8b;
typedef __attribute__((ext_vector_type(4))) float f4;
typedef __attribute__((ext_vector_type(4))) uint u4v;
typedef __attribute__((ext_vector_type(4))) ushort us4v;

__device__ __forceinline__ ushort f2b(float f) {
    __hip_bfloat16 h = __float2bfloat16(f);
    return *reinterpret_cast<ushort*>(&h);
}
__device__ __forceinline__ float b2f(ushort u) {
    unsigned v = ((unsigned)u) << 16;
    float f;
    __builtin_memcpy(&f, &v, 4);
    return f;
}
__device__ __forceinline__ float gelu_f(float h) {
    float u = 1.5957691216057308f * h * fmaf(0.044715f, h * h, 1.0f);
    float e = __expf(u);
    return h * (1.0f - __builtin_amdgcn_rcpf(e + 1.0f));
}
// swizzled index for 128-col bf16 LDS tiles (c0 multiple of 8)
__device__ __forceinline__ int swz8(int n, int c0) {
    return n * 128 + (c0 ^ ((n & 15) << 3));
}
// swizzled index, c0 multiple of 4
__device__ __forceinline__ int swz4(int n, int c0) {
    return n * 128 + (((c0 & 0x78) ^ ((n & 15) << 3)) | (c0 & 4));
}

// ---------- tiny transpose ----------
__global__ __launch_bounds__(256) void k_transpose(const float* __restrict__ in,
                                                   float* __restrict__ out,
                                                   int R, int Ccols) {
    int idx = blockIdx.x * 256 + threadIdx.x;
    if (idx >= R * Ccols) return;
    int r = idx / Ccols, c = idx % Ccols;
    out[c * R + r] = in[idx];
}

// ---------- fp32 -> bf16 ----------
__global__ __launch_bounds__(256) void k_cvt(const float* __restrict__ in,
                                             ushort* __restrict__ out, int n) {
    int i = blockIdx.x * 256 + threadIdx.x;
    if (i < n) out[i] = f2b(in[i]);
}

// ---------- pack LN1 w/b (f32 [c][n]) -> bf16 pair (uint, [n][c]), LDS-tiled ----------
__global__ __launch_bounds__(256) void k_packln(const float* __restrict__ w,
                                                const float* __restrict__ b,
                                                uint* __restrict__ out) {
    __shared__ uint tile[64 * 128];      // [n_local][c]
    const int n0 = blockIdx.x * 64;      // 512 blocks
    const int t = threadIdx.x;
    {
        const int c = t >> 1, nh = (t & 1) * 32;
        const float* wp = w + (size_t)c * N_SP + n0 + nh;
        const float* bp = b + (size_t)c * N_SP + n0 + nh;
#pragma unroll
        for (int g = 0; g < 8; ++g) {
            f4 wv = __builtin_nontemporal_load((const f4*)(wp + g * 4));
            f4 bv = __builtin_nontemporal_load((const f4*)(bp + g * 4));
            tile[(nh + g * 4 + 0) * 128 + c] = (uint)f2b(wv.x) | ((uint)f2b(bv.x) << 16);
            tile[(nh + g * 4 + 1) * 128 + c] = (uint)f2b(wv.y) | ((uint)f2b(bv.y) << 16);
            tile[(nh + g * 4 + 2) * 128 + c] = (uint)f2b(wv.z) | ((uint)f2b(bv.z) << 16);
            tile[(nh + g * 4 + 3) * 128 + c] = (uint)f2b(wv.w) | ((uint)f2b(bv.w) << 16);
        }
    }
    __syncthreads();
    uint* op = out + (size_t)n0 * 128;
#pragma unroll
    for (int g = 0; g < 8; ++g) {
        int idx = g * 256 + t;           // 2048 uint4 total
        *(uint4*)(op + idx * 4) = *(const uint4*)&tile[idx * 4];
    }
}

// ---------- covariance partials via MFMA: Gpart[b*64+kb] = X Xs^T over 512 n ----------
__global__ __launch_bounds__(256, 4) void k_cov(const float* __restrict__ x,
                                                float* __restrict__ Gpart) {
    __shared__ ushort xs[128 * 136];   // [c][n_local], pad 136 (16B-aligned rows)
    const int kb = blockIdx.x, b = blockIdx.y;
    const int t = threadIdx.x;
    const int wave = t >> 6, lane = t & 63, q = lane >> 4, r = lane & 15;
    f4 acc[8][2];
#pragma unroll
    for (int m = 0; m < 8; ++m) { acc[m][0] = (f4){0,0,0,0}; acc[m][1] = (f4){0,0,0,0}; }
    for (int ch = 0; ch < 4; ++ch) {
        const int nbase = kb * 512 + ch * 128;
        __syncthreads();
        {
            const int nq = t & 31, cr = t >> 5;      // 32 n-quads, 8 c-rows
            const float* xp = x + (size_t)b * DS + nbase + nq * 4;
#pragma unroll
            for (int half = 0; half < 2; ++half) {
                f4 xv[8];
#pragma unroll
                for (int cc = 0; cc < 8; ++cc)
                    xv[cc] = __builtin_nontemporal_load(
                        (const f4*)(xp + (size_t)(cr * 16 + half * 8 + cc) * N_SP));
#pragma unroll
                for (int cc = 0; cc < 8; ++cc) {
                    int c = cr * 16 + half * 8 + cc;
                    ushort4 pk;
                    pk.x = f2b(xv[cc].x); pk.y = f2b(xv[cc].y);
                    pk.z = f2b(xv[cc].z); pk.w = f2b(xv[cc].w);
                    *(ushort4*)&xs[c * 136 + nq * 4] = pk;
                }
            }
        }
        __syncthreads();
        for (int kk = 0; kk < 4; ++kk) {
            const int c0 = kk * 32 + q * 8;
            s8b bj0 = *(const s8b*)&xs[(wave * 32 + r) * 136 + c0];
            s8b bj1 = *(const s8b*)&xs[(wave * 32 + 16 + r) * 136 + c0];
#pragma unroll
            for (int m = 0; m < 8; ++m) {
                s8b a = *(const s8b*)&xs[(m * 16 + r) * 136 + c0];
                acc[m][0] = __builtin_amdgcn_mfma_f32_16x16x32_bf16(a, bj0, acc[m][0], 0, 0, 0);
                acc[m][1] = __builtin_amdgcn_mfma_f32_16x16x32_bf16(a, bj1, acc[m][1], 0, 0, 0);
            }
        }
    }
    float* gp = Gpart + ((size_t)b * 64 + kb) * 16384;
#pragma unroll
    for (int n2 = 0; n2 < 2; ++n2)
#pragma unroll
        for (int m = 0; m < 8; ++m)
#pragma unroll
            for (int rg = 0; rg < 4; ++rg) {
                int i = m * 16 + q * 4 + rg;
                int j = wave * 32 + n2 * 16 + r;
                gp[i * 128 + j] = acc[m][n2][rg];
            }
}

__global__ __launch_bounds__(256) void k_greduce(const float* __restrict__ Gpart,
                                                 float* __restrict__ G) {
    int tid = blockIdx.x * 256 + threadIdx.x;
    int b = tid >> 14, ij = tid & 16383;
    float s = 0.f;
#pragma unroll 8
    for (int kb = 0; kb < 64; ++kb)
        s += __builtin_nontemporal_load(&Gpart[((size_t)b * 64 + kb) * 16384 + ij]);
    G[tid] = s;
}

// ---------- gram + softmax ----------
__global__ __launch_bounds__(256) void k_gram_small(const float* __restrict__ G,
                                                    const float* __restrict__ qkv_w,
                                                    float* __restrict__ attn) {
    __shared__ float t1[16 * 132];
    __shared__ float sg[16 * 16];
    const int bh = blockIdx.x;
    const int b = bh >> 3, h = bh & 7;
    const int t = threadIdx.x;
    {
        const int i = t >> 4, c20 = (t & 15) * 8;
        const float* wq = qkv_w + (size_t)(h * 16 + i) * 128;
        const float* Gb = G + (size_t)b * 16384;
        float a[8];
#pragma unroll
        for (int k = 0; k < 8; ++k) a[k] = 0.f;
        for (int c = 0; c < 128; ++c) {
            float w = wq[c];
            const float* grow = Gb + c * 128 + c20;
#pragma unroll
            for (int k = 0; k < 8; ++k) a[k] = fmaf(w, grow[k], a[k]);
        }
#pragma unroll
        for (int k = 0; k < 8; ++k) t1[i * 132 + c20 + k] = a[k];
    }
    __syncthreads();
    {
        const int i = t >> 4, j = t & 15;
        const float* wk = qkv_w + (size_t)(128 + h * 16 + j) * 128;
        float s = 0.f;
        for (int c2 = 0; c2 < 128; ++c2) s = fmaf(t1[i * 132 + c2], wk[c2], s);
        sg[i * 16 + j] = s * 0.25f;
    }
    __syncthreads();
    if (t < 16) {
        float mx = -1e30f;
#pragma unroll
        for (int j = 0; j < 16; ++j) mx = fmaxf(mx, sg[t * 16 + j]);
        float e[16], sum = 0.f;
#pragma unroll
        for (int j = 0; j < 16; ++j) { e[j] = expf(sg[t * 16 + j] - mx); sum += e[j]; }
        float inv = 1.0f / sum;
#pragma unroll
        for (int j = 0; j < 16; ++j)
            attn[((size_t)bh * 16 + t) * 16 + j] = e[j] * inv;
    }
}

// ---------- fold: Mbb[b][o][c] = bf16( (P . blockdiag(attn) . Wv)[o][c] ) ----------
// 32 blocks: (4 c-slices x 8 b). Full-ci per thread -> no combine phase.
__global__ __launch_bounds__(256, 2) void k_mfold(const float* __restrict__ attn,
                                                  const float* __restrict__ qkv_w,
                                                  const float* __restrict__ PT,
                                                  ushort* __restrict__ Mbb) {
    __shared__ float t2[128 * 33];       // S[ci][c-slice of 32], pad 33
    const int c0b = blockIdx.x * 32;
    const int b = blockIdx.y;
    const int t = threadIdx.x;
    {
        // phase 1: S[hi][c] for c in slice; thread: hi = t&127, 16 c
        const int hi = t & 127, cg2 = (t >> 7) * 16;
        const int h = hi >> 4;
        const float* at = attn + ((size_t)b * 128 + hi) * 16;
        float a[16];
#pragma unroll
        for (int j = 0; j < 16; ++j) a[j] = at[j];
        float sc[16];
#pragma unroll
        for (int c = 0; c < 16; ++c) sc[c] = 0.f;
        for (int j = 0; j < 16; ++j) {
            const float* wv = qkv_w + (size_t)(256 + h * 16 + j) * 128 + c0b + cg2;
            float aj = a[j];
#pragma unroll
            for (int c = 0; c < 16; ++c) sc[c] = fmaf(aj, wv[c], sc[c]);
        }
#pragma unroll
        for (int c = 0; c < 16; ++c) t2[hi * 33 + cg2 + c] = sc[c];
    }
    __syncthreads();
    // phase 2: M[o][c] = sum_ci P[o][ci] S[ci][c]; thread: c = c0b+(t&31), 16 o
    const int cl = t & 31, og = t >> 5;
    float acc[16];
#pragma unroll
    for (int o = 0; o < 16; ++o) acc[o] = 0.f;
    for (int ci = 0; ci < 128; ++ci) {
        float s = t2[ci * 33 + cl];
        const float* pt = PT + ci * 128 + og * 16;
#pragma unroll
        for (int o = 0; o < 16; ++o) acc[o] = fmaf(pt[o], s, acc[o]);
    }
    ushort* m = Mbb + (size_t)b * 16384;
#pragma unroll
    for (int o = 0; o < 16; ++o)
        m[(size_t)(og * 16 + o) * 128 + c0b + cl] = f2b(acc[o]);
}

// ---------- attnproj: x1pre = Mb x + proj_b + x -> x1Tb[b][n][c] bf16, LN1 stats ----------
// 128-n tile, 512 threads / 8 waves; wave owns 16 o-rows. launch_bounds(512,2):
// no register cap (R13's spill trap).
__global__ __launch_bounds__(512, 2) void k_attnproj(const float* __restrict__ x,
                                                     const ushort* __restrict__ Mbb,
                                                     const float* __restrict__ proj_b,
                                                     ushort* __restrict__ x1Tb,
                                                     float* __restrict__ st) {
    __shared__ ushort xT[128 * 136];   // [n][c] bf16, pad 136
    const int b = blockIdx.y;
    const int n0 = blockIdx.x * 128;
    const int t = threadIdx.x;
    const int wave = t >> 6, lane = t & 63, q = lane >> 4, r = lane & 15;
    {
        // staging: 2 batches of 4 nt f4 loads + 4x4 register transpose
        const int nq = (t & 31) * 4;                 // 32 n-quads cover 128 n
        const int cg = (t >> 5) * 4;                 // 16 groups of 4 c
        const float* xb = x + (size_t)b * DS + n0 + nq;
#pragma unroll
        for (int u2 = 0; u2 < 2; ++u2) {
            int c0 = cg + u2 * 64;
            f4 xv[4];
#pragma unroll
            for (int u = 0; u < 4; ++u)
                xv[u] = __builtin_nontemporal_load((const f4*)(xb + (size_t)(c0 + u) * N_SP));
#pragma unroll
            for (int i = 0; i < 4; ++i) {
                us4v pk = { f2b(xv[0][i]), f2b(xv[1][i]),
                            f2b(xv[2][i]), f2b(xv[3][i]) };
                *(us4v*)&xT[(nq + i) * 136 + c0] = pk;
            }
        }
    }
    const int orow = wave * 16 + r;
    // prefetch the wave's Mb slice: 4 independent loads (overlaps barrier)
    s8b a[4];
    {
        const ushort* mp = Mbb + (size_t)b * 16384 + (size_t)orow * 128 + q * 8;
#pragma unroll
        for (int kk = 0; kk < 4; ++kk)
            a[kk] = *(const s8b*)(mp + kk * 32);
    }
    __syncthreads();
    f4 acc[8];
#pragma unroll
    for (int j = 0; j < 8; ++j) acc[j] = (f4){0,0,0,0};
#pragma unroll
    for (int kk = 0; kk < 4; ++kk) {
        const int c0 = kk * 32 + q * 8;
#pragma unroll
        for (int j = 0; j < 8; ++j) {
            s8b bx = *(const s8b*)&xT[(j * 16 + r) * 136 + c0];
            acc[j] = __builtin_amdgcn_mfma_f32_16x16x32_bf16(a[kk], bx, acc[j], 0, 0, 0);
        }
    }
    float s = 0.f, sq = 0.f;
    const int o0 = wave * 16 + q * 4;
    float4 pb = *(const float4*)&proj_b[o0];
#pragma unroll
    for (int j = 0; j < 8; ++j) {
        const int nn = j * 16 + r;
        ushort4 xr = *(const ushort4*)&xT[nn * 136 + o0];
        float v0 = acc[j][0] + pb.x + b2f(xr.x);
        float v1 = acc[j][1] + pb.y + b2f(xr.y);
        float v2 = acc[j][2] + pb.z + b2f(xr.z);
        float v3 = acc[j][3] + pb.w + b2f(xr.w);
        us4v ov = { f2b(v0), f2b(v1), f2b(v2), f2b(v3) };
        __builtin_nontemporal_store(ov,
            (us4v*)(x1Tb + (size_t)b * DS + (size_t)(n0 + nn) * 128 + o0));
        s += (v0 + v1) + (v2 + v3);
        sq = fmaf(v0, v0, sq); sq = fmaf(v1, v1, sq);
        sq = fmaf(v2, v2, sq); sq = fmaf(v3, v3, sq);
    }
#pragma unroll
    for (int off = 32; off > 0; off >>= 1) {
        s += __shfl_down(s, off, 64);
        sq += __shfl_down(sq, off, 64);
    }
    if (lane == 0) {
        atomicAdd(&st[0 + b], s);
        atomicAdd(&st[8 + b], sq);
    }
}

__global__ void k_finalize(float* st, int off) {
    int b = threadIdx.x;
    if (b < 8) {
        const float invn = 1.0f / 4194304.0f;
        float mu = st[off + b] * invn;
        float var = st[off + 8 + b] * invn - mu * mu;
        st[off + 16 + b] = mu;
        st[off + 24 + b] = rsqrtf(var + 1e-5f);
    }
}

// ---------- LN2 apply, direct f32 params ----------
__global__ __launch_bounds__(256) void k_lnapply(const float* __restrict__ in,
                                                 const float* __restrict__ lnw,
                                                 const float* __restrict__ lnb,
                                                 const float* __restrict__ st, int off,
                                                 float* __restrict__ out) {
    size_t i4 = (size_t)blockIdx.x * 256 + threadIdx.x;
    int b = (int)(i4 >> 20);
    size_t cn = i4 * 4 - (size_t)b * 4194304;
    float mu = st[off + 16 + b], rs = st[off + 24 + b];
    const float4 xv = *(const float4*)(in + (size_t)b * DS + cn);
    const float4 wv = *(const float4*)(lnw + cn);
    const float4 bv = *(const float4*)(lnb + cn);
    float4 o;
    o.x = fmaf((xv.x - mu) * rs, wv.x, bv.x);
    o.y = fmaf((xv.y - mu) * rs, wv.y, bv.y);
    o.z = fmaf((xv.z - mu) * rs, wv.z, bv.z);
    o.w = fmaf((xv.w - mu) * rs, wv.w, bv.w);
    *(float4*)(out + (size_t)b * DS + cn) = o;
}

// ---------- fused LN1-apply + MLP + residual + LN2 stats ----------
// 128-n tile, 512 threads / 8 waves, launch_bounds(512,2): no register cap.
// Wave owns 16 output rows per GEMM phase. Staging: 2 batches of 2 rows.
__global__ __launch_bounds__(512, 2) void k_mlp(const ushort* __restrict__ x1Tb,
                                                float* __restrict__ xout,
                                                const ushort* __restrict__ w1b,
                                                const float* __restrict__ b1v,
                                                const ushort* __restrict__ w2b,
                                                const float* __restrict__ b2v,
                                                const uint* __restrict__ lnwbT,
                                                float* __restrict__ st) {
    __shared__ ushort xT[128 * 128];   // swizzled, x1 = LN1(x1pre) bf16
    __shared__ ushort hT[128 * 128];   // swizzled, gelu os-slice [n][hr] bf16
    const int b = blockIdx.y;
    const int n0 = blockIdx.x * 128;
    const int t = threadIdx.x;
    const int wave = t >> 6, lane = t & 63, q = lane >> 4, r = lane & 15;
    const float mu = st[16 + b], rs = st[24 + b];
    {
        // staging: 4 rows x 8 c per thread; 2 batches of 2 rows (6 loads each)
        const int c8 = (t & 15) * 8, rb = t >> 4;    // rb in 0..31
        const ushort* xb = x1Tb + (size_t)b * DS + (size_t)n0 * 128;
        const uint*  wb = lnwbT + (size_t)n0 * 128;
#pragma unroll
        for (int gb = 0; gb < 2; ++gb) {
            s8b xv[2]; u4v wv0[2], wv1[2];
#pragma unroll
            for (int u = 0; u < 2; ++u) {
                int nn = (gb * 2 + u) * 32 + rb;
                xv[u]  = __builtin_nontemporal_load((const s8b*)(xb + (size_t)nn * 128 + c8));
                wv0[u] = __builtin_nontemporal_load((const u4v*)(wb + (size_t)nn * 128 + c8));
                wv1[u] = __builtin_nontemporal_load((const u4v*)(wb + (size_t)nn * 128 + c8 + 4));
            }
#pragma unroll
            for (int u = 0; u < 2; ++u) {
                int nn = (gb * 2 + u) * 32 + rb;
                ushort4 p0, p1;
                float xe;
                xe = b2f((ushort)xv[u][0]);
                p0.x = f2b(fmaf((xe - mu) * rs, b2f((ushort)(wv0[u].x & 0xffffu)), b2f((ushort)(wv0[u].x >> 16))));
                xe = b2f((ushort)xv[u][1]);
                p0.y = f2b(fmaf((xe - mu) * rs, b2f((ushort)(wv0[u].y & 0xffffu)), b2f((ushort)(wv0[u].y >> 16))));
                xe = b2f((ushort)xv[u][2]);
                p0.z = f2b(fmaf((xe - mu) * rs, b2f((ushort)(wv0[u].z & 0xffffu)), b2f((ushort)(wv0[u].z >> 16))));
                xe = b2f((ushort)xv[u][3]);
                p0.w = f2b(fmaf((xe - mu) * rs, b2f((ushort)(wv0[u].w & 0xffffu)), b2f((ushort)(wv0[u].w >> 16))));
                xe = b2f((ushort)xv[u][4]);
                p1.x = f2b(fmaf((xe - mu) * rs, b2f((ushort)(wv1[u].x & 0xffffu)), b2f((ushort)(wv1[u].x >> 16))));
                xe = b2f((ushort)xv[u][5]);
                p1.y = f2b(fmaf((xe - mu) * rs, b2f((ushort)(wv1[u].y & 0xffffu)), b2f((ushort)(wv1[u].y >> 16))));
                xe = b2f((ushort)xv[u][6]);
                p1.z = f2b(fmaf((xe - mu) * rs, b2f((ushort)(wv1[u].z & 0xffffu)), b2f((ushort)(wv1[u].z >> 16))));
                xe = b2f((ushort)xv[u][7]);
                p1.w = f2b(fmaf((xe - mu) * rs, b2f((ushort)(wv1[u].w & 0xffffu)), b2f((ushort)(wv1[u].w >> 16))));
                *(ushort4*)&xT[swz4(nn, c8)] = p0;
                *(ushort4*)&xT[swz4(nn, c8 + 4)] = p1;
            }
        }
    }
    const int orow = wave * 16 + r;
    // prefetch GEMM1 A-slice for os=0 (4 independent loads), overlaps barrier
    s8b a1[4];
    {
        const ushort* w1p = w1b + (size_t)orow * 128 + q * 8;
#pragma unroll
        for (int kk = 0; kk < 4; ++kk)
            a1[kk] = *(const s8b*)(w1p + kk * 32);
    }
    __syncthreads();
    // acc2 initialized with b2 (bias folded into MFMA C-in)
    const int o0 = wave * 16 + q * 4;
    float4 b2q = *(const float4*)&b2v[o0];
    f4 acc2[8];
#pragma unroll
    for (int j = 0; j < 8; ++j)
        acc2[j] = (f4){b2q.x, b2q.y, b2q.z, b2q.w};

    for (int os = 0; os < 4; ++os) {
        // ---- GEMM1: h[wave's 16 rows of os-slice] = W1 x1 + b1 (C-in) ----
        float4 b1q = *(const float4*)&b1v[os * 128 + o0];
        f4 acc1[8];
#pragma unroll
        for (int j = 0; j < 8; ++j)
            acc1[j] = (f4){b1q.x, b1q.y, b1q.z, b1q.w};
#pragma unroll
        for (int kk = 0; kk < 4; ++kk) {
            const int c0 = kk * 32 + q * 8;
#pragma unroll
            for (int j = 0; j < 8; ++j) {
                s8b bx = *(const s8b*)&xT[swz8(j * 16 + r, c0)];
                acc1[j] = __builtin_amdgcn_mfma_f32_16x16x32_bf16(a1[kk], bx, acc1[j], 0, 0, 0);
            }
        }
        // prefetch GEMM2 A-slice for this os (independent of hT)
        s8b a2[4];
        {
            const ushort* w2p = w2b + (size_t)orow * 512 + os * 128 + q * 8;
#pragma unroll
            for (int kk = 0; kk < 4; ++kk)
                a2[kk] = *(const s8b*)(w2p + kk * 32);
        }
        // ---- gelu -> hT (cross-wave); hr0 = wave's rows ----
        const int hr0 = wave * 16 + q * 4;
#pragma unroll
        for (int j = 0; j < 8; ++j) {
            ushort4 pk;
            pk.x = f2b(gelu_f(acc1[j][0]));
            pk.y = f2b(gelu_f(acc1[j][1]));
            pk.z = f2b(gelu_f(acc1[j][2]));
            pk.w = f2b(gelu_f(acc1[j][3]));
            *(ushort4*)&hT[swz4(j * 16 + r, hr0)] = pk;
        }
        __syncthreads();   // hT complete across waves
        // ---- GEMM2: acc2 += W2[:, os-slice] h ----
#pragma unroll
        for (int kk = 0; kk < 4; ++kk) {
            const int c0 = kk * 32 + q * 8;
#pragma unroll
            for (int j = 0; j < 8; ++j) {
                s8b hx = *(const s8b*)&hT[swz8(j * 16 + r, c0)];
                acc2[j] = __builtin_amdgcn_mfma_f32_16x16x32_bf16(a2[kk], hx, acc2[j], 0, 0, 0);
            }
        }
        // prefetch next os's GEMM1 A-slice (overlaps barrier drain)
        if (os < 3) {
            const ushort* w1p = w1b + (size_t)((os + 1) * 128 + orow) * 128 + q * 8;
#pragma unroll
            for (int kk = 0; kk < 4; ++kk)
                a1[kk] = *(const s8b*)(w1p + kk * 32);
        }
        __syncthreads();   // hT consumed; safe to overwrite next os
    }
    // ---- epilogue: residual (b2 already in acc2), normal strided store, LN2 stats ----
    float s = 0.f, sq = 0.f;
#pragma unroll
    for (int j = 0; j < 8; ++j) {
        const int nn = j * 16 + r;
        ushort4 xr = *(const ushort4*)&xT[swz4(nn, o0)];
        float v0 = acc2[j][0] + b2f(xr.x);
        float v1 = acc2[j][1] + b2f(xr.y);
        float v2 = acc2[j][2] + b2f(xr.z);
        float v3 = acc2[j][3] + b2f(xr.w);
        float* op = xout + (size_t)b * DS + n0 + nn;
        op[(size_t)(o0 + 0) * N_SP] = v0;
        op[(size_t)(o0 + 1) * N_SP] = v1;
        op[(size_t)(o0 + 2) * N_SP] = v2;
        op[(size_t)(o0 + 3) * N_SP] = v3;
        s += (v0 + v1) + (v2 + v3);
        sq = fmaf(v0, v0, sq); sq = fmaf(v1, v1, sq);
        sq = fmaf(v2, v2, sq); sq = fmaf(v3, v3, sq);
    }
#pragma unroll
    for (int off = 32; off > 0; off >>= 1) {
        s += __shfl_down(s, off, 64);
        sq += __shfl_down(sq, off, 64);
    }
    if (lane == 0) {
        atomicAdd(&st[32 + b], s);
        atomicAdd(&st[40 + b], sq);
    }
}

extern "C" void kernel_launch(void* const* d_in, const int* in_sizes, int n_in,
                              void* d_out, int out_size, void* d_ws, size_t ws_size,
                              hipStream_t stream) {
    const float* x      = (const float*)d_in[0];
    const float* qkv_w  = (const float*)d_in[1];
    const float* proj_w = (const float*)d_in[2];
    const float* proj_b = (const float*)d_in[3];
    const float* ln1_w  = (const float*)d_in[4];
    const float* ln1_b  = (const float*)d_in[5];
    const float* ln2_w  = (const float*)d_in[6];
    const float* ln2_b  = (const float*)d_in[7];
    const float* mlp_w1 = (const float*)d_in[8];
    const float* mlp_b1 = (const float*)d_in[9];
    const float* mlp_w2 = (const float*)d_in[10];
    const float* mlp_b2 = (const float*)d_in[11];
    float* out = (float*)d_out;

    char* wsb = (char*)d_ws;
    // small persistent region
    float*  st    = (float*)wsb;                      // 256 B
    float*  attn  = (float*)(wsb + 256);              // 65,536
    float*  PT    = (float*)(wsb + 65792);            // 65,536
    ushort* Mbb   = (ushort*)(wsb + 131328);          // 262,144
    ushort* w1b   = (ushort*)(wsb + 393472);          // 131,072
    ushort* w2b   = (ushort*)(wsb + 524544);          // 131,072
    float*  G     = (float*)(wsb + 655616);           // 524,288
    uint*   lnwbT = (uint*)(wsb + 1179904);           // 16,777,216
    // big dual-use region (stream-ordered lifetimes):
    //   Gpart (33.5MB, dead after k_greduce) -> x1Tb bf16 (67MB, dead after k_mlp)
    float*  Gpart = (float*)(wsb + 18874368);         // 33,554,432
    ushort* x1Tb  = (ushort*)(wsb + 18874368);        // 67,108,864

    hipMemsetAsync(st, 0, 64 * sizeof(float), stream);

    k_transpose<<<64, 256, 0, stream>>>(proj_w, PT, 128, 128);
    k_cvt<<<256, 256, 0, stream>>>(mlp_w1, w1b, 65536);
    k_cvt<<<256, 256, 0, stream>>>(mlp_w2, w2b, 65536);
    k_packln<<<512, 256, 0, stream>>>(ln1_w, ln1_b, lnwbT);

    k_cov<<<dim3(64, 8), 256, 0, stream>>>(x, Gpart);
    k_greduce<<<512, 256, 0, stream>>>(Gpart, G);
    k_gram_small<<<64, 256, 0, stream>>>(G, qkv_w, attn);
    k_mfold<<<dim3(4, 8), 256, 0, stream>>>(attn, qkv_w, PT, Mbb);

    k_attnproj<<<dim3(256, 8), 512, 0, stream>>>(x, Mbb, proj_b, x1Tb, st);
    k_finalize<<<1, 64, 0, stream>>>(st, 0);
    k_mlp<<<dim3(256, 8), 512, 0, stream>>>(x1Tb, out, w1b, mlp_b1, w2b, mlp_b2,
                                            lnwbT, st);
    k_finalize<<<1, 64, 0, stream>>>(st, 32);
    k_lnapply<<<32768, 256, 0, stream>>>(out, ln2_w, ln2_b, st, 32, out);
}

// Round 11
// 887.913 us; speedup vs baseline: 1.4594x; 1.4594x over previous
//
#include <hip/hip_runtime.h>
#include <hip/hip_bf16.h>
#include <math.h>

// TransformerBlock3D: B=8, C=128, S=32 (N=32768), HEADS=8 (dim_head=16), MLP=512
// Round 15: consolidate on the R12 optimum + fixed-overhead removal.
//  Occupancy lever conclusively dead (R7/R9/R13/R14: dur x MfmaUtil ~2780
//  invariant; halving rows/wave doubles LDS B-frag reads; more waves never
//  helped). R12 shapes (256t, 128-n) restored for k_mlp/k_attnproj.
//  - k_finalize deleted: mu/rs computed inline from raw sums (2 flops).
//  - prep kernels (transpose, 2x cvt, packln) merged into one k_prep.
//  - 13 -> 9 launches.
// Math: G=XX^T, attn=softmax(0.25*WqGWk^T), Mb=P.blockdiag(attn).Wv (bf16),
//       x1pre = Mb x + proj_b + x; x1 = LN1(x1pre); x2pre = x1 + b2 + W2 gelu(W1 x1 + b1).

#define N_SP 32768
typedef __hip_bfloat16 bf16;
static const size_t DS = (size_t)128 * N_SP;

typedef __attribute__((ext_vector_type(8))) short s8b;
typedef __attribute__((ext_vector_type(4))) float f4;
typedef __attribute__((ext_vector_type(4))) uint u4v;
typedef __attribute__((ext_vector_type(4))) ushort us4v;

__device__ __forceinline__ ushort f2b(float f) {
    __hip_bfloat16 h = __float2bfloat16(f);
    return *reinterpret_cast<ushort*>(&h);
}
__device__ __forceinline__ float b2f(ushort u) {
    unsigned v = ((unsigned)u) << 16;
    float f;
    __builtin_memcpy(&f, &v, 4);
    return f;
}
__device__ __forceinline__ float gelu_f(float h) {
    float u = 1.5957691216057308f * h * fmaf(0.044715f, h * h, 1.0f);
    float e = __expf(u);
    return h * (1.0f - __builtin_amdgcn_rcpf(e + 1.0f));
}
// LN stats from raw sums (replaces k_finalize; identical arithmetic)
__device__ __forceinline__ void ln_stats(const float* st, int off, int b,
                                         float& mu, float& rs) {
    const float invn = 1.0f / 4194304.0f;
    mu = st[off + b] * invn;
    float var = st[off + 8 + b] * invn - mu * mu;
    rs = rsqrtf(var + 1e-5f);
}
// swizzled index for 128-col bf16 LDS tiles (c0 multiple of 8)
__device__ __forceinline__ int swz8(int n, int c0) {
    return n * 128 + (c0 ^ ((n & 15) << 3));
}
// swizzled index, c0 multiple of 4
__device__ __forceinline__ int swz4(int n, int c0) {
    return n * 128 + (((c0 & 0x78) ^ ((n & 15) << 3)) | (c0 & 4));
}

// ---------- merged prep: packln (512 blocks) | transpose (64) | cvt w1 (256) | cvt w2 (256) ----------
__global__ __launch_bounds__(256) void k_prep(const float* __restrict__ proj_w,
                                              float* __restrict__ PT,
                                              const float* __restrict__ mlp_w1,
                                              ushort* __restrict__ w1b,
                                              const float* __restrict__ mlp_w2,
                                              ushort* __restrict__ w2b,
                                              const float* __restrict__ ln1w,
                                              const float* __restrict__ ln1b,
                                              uint* __restrict__ lnwbT) {
    __shared__ uint tile[64 * 128];
    const int bx = blockIdx.x, t = threadIdx.x;
    if (bx < 512) {
        // pack LN1 w/b (f32 [c][n]) -> bf16 pair (uint, [n][c]), LDS-tiled
        const int n0 = bx * 64;
        {
            const int c = t >> 1, nh = (t & 1) * 32;
            const float* wp = ln1w + (size_t)c * N_SP + n0 + nh;
            const float* bp = ln1b + (size_t)c * N_SP + n0 + nh;
#pragma unroll
            for (int g = 0; g < 8; ++g) {
                f4 wv = __builtin_nontemporal_load((const f4*)(wp + g * 4));
                f4 bv = __builtin_nontemporal_load((const f4*)(bp + g * 4));
                tile[(nh + g * 4 + 0) * 128 + c] = (uint)f2b(wv.x) | ((uint)f2b(bv.x) << 16);
                tile[(nh + g * 4 + 1) * 128 + c] = (uint)f2b(wv.y) | ((uint)f2b(bv.y) << 16);
                tile[(nh + g * 4 + 2) * 128 + c] = (uint)f2b(wv.z) | ((uint)f2b(bv.z) << 16);
                tile[(nh + g * 4 + 3) * 128 + c] = (uint)f2b(wv.w) | ((uint)f2b(bv.w) << 16);
            }
        }
        __syncthreads();
        uint* op = lnwbT + (size_t)n0 * 128;
#pragma unroll
        for (int g = 0; g < 8; ++g) {
            int idx = g * 256 + t;
            *(uint4*)(op + idx * 4) = *(const uint4*)&tile[idx * 4];
        }
    } else if (bx < 576) {
        int idx = (bx - 512) * 256 + t;          // 16384 elements
        int r = idx >> 7, c = idx & 127;
        PT[c * 128 + r] = proj_w[idx];
    } else if (bx < 832) {
        int i = (bx - 576) * 256 + t;            // 65536
        w1b[i] = f2b(mlp_w1[i]);
    } else {
        int i = (bx - 832) * 256 + t;            // 65536
        w2b[i] = f2b(mlp_w2[i]);
    }
}

// ---------- covariance partials via MFMA: Gpart[b*64+kb] = X Xs^T over 512 n ----------
__global__ __launch_bounds__(256, 4) void k_cov(const float* __restrict__ x,
                                                float* __restrict__ Gpart) {
    __shared__ ushort xs[128 * 136];   // [c][n_local], pad 136 (16B-aligned rows)
    const int kb = blockIdx.x, b = blockIdx.y;
    const int t = threadIdx.x;
    const int wave = t >> 6, lane = t & 63, q = lane >> 4, r = lane & 15;
    f4 acc[8][2];
#pragma unroll
    for (int m = 0; m < 8; ++m) { acc[m][0] = (f4){0,0,0,0}; acc[m][1] = (f4){0,0,0,0}; }
    for (int ch = 0; ch < 4; ++ch) {
        const int nbase = kb * 512 + ch * 128;
        __syncthreads();
        {
            const int nq = t & 31, cr = t >> 5;      // 32 n-quads, 8 c-rows
            const float* xp = x + (size_t)b * DS + nbase + nq * 4;
#pragma unroll
            for (int half = 0; half < 2; ++half) {
                f4 xv[8];
#pragma unroll
                for (int cc = 0; cc < 8; ++cc)
                    xv[cc] = __builtin_nontemporal_load(
                        (const f4*)(xp + (size_t)(cr * 16 + half * 8 + cc) * N_SP));
#pragma unroll
                for (int cc = 0; cc < 8; ++cc) {
                    int c = cr * 16 + half * 8 + cc;
                    ushort4 pk;
                    pk.x = f2b(xv[cc].x); pk.y = f2b(xv[cc].y);
                    pk.z = f2b(xv[cc].z); pk.w = f2b(xv[cc].w);
                    *(ushort4*)&xs[c * 136 + nq * 4] = pk;
                }
            }
        }
        __syncthreads();
        for (int kk = 0; kk < 4; ++kk) {
            const int c0 = kk * 32 + q * 8;
            s8b bj0 = *(const s8b*)&xs[(wave * 32 + r) * 136 + c0];
            s8b bj1 = *(const s8b*)&xs[(wave * 32 + 16 + r) * 136 + c0];
#pragma unroll
            for (int m = 0; m < 8; ++m) {
                s8b a = *(const s8b*)&xs[(m * 16 + r) * 136 + c0];
                acc[m][0] = __builtin_amdgcn_mfma_f32_16x16x32_bf16(a, bj0, acc[m][0], 0, 0, 0);
                acc[m][1] = __builtin_amdgcn_mfma_f32_16x16x32_bf16(a, bj1, acc[m][1], 0, 0, 0);
            }
        }
    }
    float* gp = Gpart + ((size_t)b * 64 + kb) * 16384;
#pragma unroll
    for (int n2 = 0; n2 < 2; ++n2)
#pragma unroll
        for (int m = 0; m < 8; ++m)
#pragma unroll
            for (int rg = 0; rg < 4; ++rg) {
                int i = m * 16 + q * 4 + rg;
                int j = wave * 32 + n2 * 16 + r;
                gp[i * 128 + j] = acc[m][n2][rg];
            }
}

__global__ __launch_bounds__(256) void k_greduce(const float* __restrict__ Gpart,
                                                 float* __restrict__ G) {
    int tid = blockIdx.x * 256 + threadIdx.x;
    int b = tid >> 14, ij = tid & 16383;
    float s = 0.f;
#pragma unroll 8
    for (int kb = 0; kb < 64; ++kb)
        s += __builtin_nontemporal_load(&Gpart[((size_t)b * 64 + kb) * 16384 + ij]);
    G[tid] = s;
}

// ---------- gram + softmax ----------
__global__ __launch_bounds__(256) void k_gram_small(const float* __restrict__ G,
                                                    const float* __restrict__ qkv_w,
                                                    float* __restrict__ attn) {
    __shared__ float t1[16 * 132];
    __shared__ float sg[16 * 16];
    const int bh = blockIdx.x;
    const int b = bh >> 3, h = bh & 7;
    const int t = threadIdx.x;
    {
        const int i = t >> 4, c20 = (t & 15) * 8;
        const float* wq = qkv_w + (size_t)(h * 16 + i) * 128;
        const float* Gb = G + (size_t)b * 16384;
        float a[8];
#pragma unroll
        for (int k = 0; k < 8; ++k) a[k] = 0.f;
        for (int c = 0; c < 128; ++c) {
            float w = wq[c];
            const float* grow = Gb + c * 128 + c20;
#pragma unroll
            for (int k = 0; k < 8; ++k) a[k] = fmaf(w, grow[k], a[k]);
        }
#pragma unroll
        for (int k = 0; k < 8; ++k) t1[i * 132 + c20 + k] = a[k];
    }
    __syncthreads();
    {
        const int i = t >> 4, j = t & 15;
        const float* wk = qkv_w + (size_t)(128 + h * 16 + j) * 128;
        float s = 0.f;
        for (int c2 = 0; c2 < 128; ++c2) s = fmaf(t1[i * 132 + c2], wk[c2], s);
        sg[i * 16 + j] = s * 0.25f;
    }
    __syncthreads();
    if (t < 16) {
        float mx = -1e30f;
#pragma unroll
        for (int j = 0; j < 16; ++j) mx = fmaxf(mx, sg[t * 16 + j]);
        float e[16], sum = 0.f;
#pragma unroll
        for (int j = 0; j < 16; ++j) { e[j] = expf(sg[t * 16 + j] - mx); sum += e[j]; }
        float inv = 1.0f / sum;
#pragma unroll
        for (int j = 0; j < 16; ++j)
            attn[((size_t)bh * 16 + t) * 16 + j] = e[j] * inv;
    }
}

// ---------- fold: Mbb[b][o][c] = bf16( (P . blockdiag(attn) . Wv)[o][c] ) ----------
// 32 blocks: (4 c-slices x 8 b). Full-ci per thread -> no combine phase.
__global__ __launch_bounds__(256, 2) void k_mfold(const float* __restrict__ attn,
                                                  const float* __restrict__ qkv_w,
                                                  const float* __restrict__ PT,
                                                  ushort* __restrict__ Mbb) {
    __shared__ float t2[128 * 33];       // S[ci][c-slice of 32], pad 33
    const int c0b = blockIdx.x * 32;
    const int b = blockIdx.y;
    const int t = threadIdx.x;
    {
        // phase 1: S[hi][c] for c in slice; thread: hi = t&127, 16 c
        const int hi = t & 127, cg2 = (t >> 7) * 16;
        const int h = hi >> 4;
        const float* at = attn + ((size_t)b * 128 + hi) * 16;
        float a[16];
#pragma unroll
        for (int j = 0; j < 16; ++j) a[j] = at[j];
        float sc[16];
#pragma unroll
        for (int c = 0; c < 16; ++c) sc[c] = 0.f;
        for (int j = 0; j < 16; ++j) {
            const float* wv = qkv_w + (size_t)(256 + h * 16 + j) * 128 + c0b + cg2;
            float aj = a[j];
#pragma unroll
            for (int c = 0; c < 16; ++c) sc[c] = fmaf(aj, wv[c], sc[c]);
        }
#pragma unroll
        for (int c = 0; c < 16; ++c) t2[hi * 33 + cg2 + c] = sc[c];
    }
    __syncthreads();
    // phase 2: M[o][c] = sum_ci P[o][ci] S[ci][c]; thread: c = c0b+(t&31), 16 o
    const int cl = t & 31, og = t >> 5;
    float acc[16];
#pragma unroll
    for (int o = 0; o < 16; ++o) acc[o] = 0.f;
    for (int ci = 0; ci < 128; ++ci) {
        float s = t2[ci * 33 + cl];
        const float* pt = PT + ci * 128 + og * 16;
#pragma unroll
        for (int o = 0; o < 16; ++o) acc[o] = fmaf(pt[o], s, acc[o]);
    }
    ushort* m = Mbb + (size_t)b * 16384;
#pragma unroll
    for (int o = 0; o < 16; ++o)
        m[(size_t)(og * 16 + o) * 128 + c0b + cl] = f2b(acc[o]);
}

// ---------- attnproj: x1pre = Mb x + proj_b + x -> x1Tb[b][n][c] bf16, LN1 stats ----------
// R12 geometry: 128-n tile, 256t; staging = 16 nt float4 loads + 4x4 reg transpose.
__global__ __launch_bounds__(256, 3) void k_attnproj(const float* __restrict__ x,
                                                     const ushort* __restrict__ Mbb,
                                                     const float* __restrict__ proj_b,
                                                     ushort* __restrict__ x1Tb,
                                                     float* __restrict__ st) {
    __shared__ ushort xT[128 * 136];   // [n][c] bf16, pad 136
    const int b = blockIdx.y;
    const int n0 = blockIdx.x * 128;
    const int t = threadIdx.x;
    const int wave = t >> 6, lane = t & 63, q = lane >> 4, r = lane & 15;
    {
        const int nq = (t & 31) * 4;                 // 32 n-quads cover 128 n
        const int cg = (t >> 5) * 4;                 // 8 c-quads base
        const float* xb = x + (size_t)b * DS + n0 + nq;
#pragma unroll
        for (int ph = 0; ph < 2; ++ph) {
            f4 xv[8];
#pragma unroll
            for (int u = 0; u < 8; ++u) {
                int c = ph * 64 + cg + (u >> 2) * 32 + (u & 3);
                xv[u] = __builtin_nontemporal_load((const f4*)(xb + (size_t)c * N_SP));
            }
#pragma unroll
            for (int u2 = 0; u2 < 2; ++u2) {
                int c0 = ph * 64 + cg + u2 * 32;
#pragma unroll
                for (int i = 0; i < 4; ++i) {
                    us4v pk = { f2b(xv[u2 * 4 + 0][i]), f2b(xv[u2 * 4 + 1][i]),
                                f2b(xv[u2 * 4 + 2][i]), f2b(xv[u2 * 4 + 3][i]) };
                    *(us4v*)&xT[(nq + i) * 136 + c0] = pk;
                }
            }
        }
    }
    const int orow = wave * 32 + r;
    // prefetch the wave's Mb slice: 8 independent loads (overlaps barrier)
    s8b a[8];
    {
        const ushort* mp = Mbb + (size_t)b * 16384 + (size_t)orow * 128 + q * 8;
#pragma unroll
        for (int m = 0; m < 2; ++m)
#pragma unroll
            for (int kk = 0; kk < 4; ++kk)
                a[m * 4 + kk] = *(const s8b*)(mp + m * 16 * 128 + kk * 32);
    }
    __syncthreads();
    f4 acc[2][8];
#pragma unroll
    for (int m = 0; m < 2; ++m)
#pragma unroll
        for (int j = 0; j < 8; ++j) acc[m][j] = (f4){0,0,0,0};
#pragma unroll
    for (int kk = 0; kk < 4; ++kk) {
        const int c0 = kk * 32 + q * 8;
#pragma unroll
        for (int j = 0; j < 8; ++j) {
            s8b bx = *(const s8b*)&xT[(j * 16 + r) * 136 + c0];
            acc[0][j] = __builtin_amdgcn_mfma_f32_16x16x32_bf16(a[kk],     bx, acc[0][j], 0, 0, 0);
            acc[1][j] = __builtin_amdgcn_mfma_f32_16x16x32_bf16(a[4 + kk], bx, acc[1][j], 0, 0, 0);
        }
    }
    float s = 0.f, sq = 0.f;
    float4 pbq0 = *(const float4*)&proj_b[wave * 32 + q * 4];
    float4 pbq1 = *(const float4*)&proj_b[wave * 32 + 16 + q * 4];
    // j-outer/m-inner: both 8B halves of each 64B x1Tb line stored adjacently
#pragma unroll
    for (int j = 0; j < 8; ++j) {
        const int nn = j * 16 + r;
        ushort* obase = x1Tb + (size_t)b * DS + (size_t)(n0 + nn) * 128;
#pragma unroll
        for (int m = 0; m < 2; ++m) {
            const int o0 = wave * 32 + m * 16 + q * 4;
            const float4 pb = m ? pbq1 : pbq0;
            ushort4 xr = *(const ushort4*)&xT[nn * 136 + o0];
            float v0 = acc[m][j][0] + pb.x + b2f(xr.x);
            float v1 = acc[m][j][1] + pb.y + b2f(xr.y);
            float v2 = acc[m][j][2] + pb.z + b2f(xr.z);
            float v3 = acc[m][j][3] + pb.w + b2f(xr.w);
            us4v ov = { f2b(v0), f2b(v1), f2b(v2), f2b(v3) };
            __builtin_nontemporal_store(ov, (us4v*)(obase + o0));
            s += (v0 + v1) + (v2 + v3);
            sq = fmaf(v0, v0, sq); sq = fmaf(v1, v1, sq);
            sq = fmaf(v2, v2, sq); sq = fmaf(v3, v3, sq);
        }
    }
#pragma unroll
    for (int off = 32; off > 0; off >>= 1) {
        s += __shfl_down(s, off, 64);
        sq += __shfl_down(sq, off, 64);
    }
    if (lane == 0) {
        atomicAdd(&st[0 + b], s);
        atomicAdd(&st[8 + b], sq);
    }
}

// ---------- LN2 apply, direct f32 params; stats inline from raw sums ----------
__global__ __launch_bounds__(256) void k_lnapply(const float* __restrict__ in,
                                                 const float* __restrict__ lnw,
                                                 const float* __restrict__ lnb,
                                                 const float* __restrict__ st,
                                                 float* __restrict__ out) {
    size_t i4 = (size_t)blockIdx.x * 256 + threadIdx.x;
    int b = (int)(i4 >> 20);
    size_t cn = i4 * 4 - (size_t)b * 4194304;
    float mu, rs;
    ln_stats(st, 32, b, mu, rs);
    const float4 xv = *(const float4*)(in + (size_t)b * DS + cn);
    const float4 wv = *(const float4*)(lnw + cn);
    const float4 bv = *(const float4*)(lnb + cn);
    float4 o;
    o.x = fmaf((xv.x - mu) * rs, wv.x, bv.x);
    o.y = fmaf((xv.y - mu) * rs, wv.y, bv.y);
    o.z = fmaf((xv.z - mu) * rs, wv.z, bv.z);
    o.w = fmaf((xv.w - mu) * rs, wv.w, bv.w);
    *(float4*)(out + (size_t)b * DS + cn) = o;
}

// ---------- fused LN1-apply + MLP + residual + LN2 stats, 128-n tile (R12) ----------
__global__ __launch_bounds__(256, 2) void k_mlp(const ushort* __restrict__ x1Tb,
                                                float* __restrict__ xout,
                                                const ushort* __restrict__ w1b,
                                                const float* __restrict__ b1v,
                                                const ushort* __restrict__ w2b,
                                                const float* __restrict__ b2v,
                                                const uint* __restrict__ lnwbT,
                                                float* __restrict__ st) {
    __shared__ ushort xT[128 * 128];   // swizzled, x1 = LN1(x1pre) bf16
    __shared__ ushort hT[128 * 128];   // swizzled, gelu os-slice [n][hr] bf16
    const int b = blockIdx.y;
    const int n0 = blockIdx.x * 128;
    const int t = threadIdx.x;
    const int wave = t >> 6, lane = t & 63, q = lane >> 4, r = lane & 15;
    float mu, rs;
    ln_stats(st, 0, b, mu, rs);
    {
        // 16 col-groups of 8 c x 16 rows/pass; 2 batches, 12 nt loads in flight
        const int c8 = (t & 15) * 8, rb = t >> 4;
        const ushort* xb = x1Tb + (size_t)b * DS + (size_t)n0 * 128;
        const uint*  wb = lnwbT + (size_t)n0 * 128;
#pragma unroll
        for (int gb = 0; gb < 2; ++gb) {
            s8b xv[4]; u4v wv0[4], wv1[4];
#pragma unroll
            for (int u = 0; u < 4; ++u) {
                int nn = (gb * 4 + u) * 16 + rb;
                xv[u]  = __builtin_nontemporal_load((const s8b*)(xb + (size_t)nn * 128 + c8));
                wv0[u] = __builtin_nontemporal_load((const u4v*)(wb + (size_t)nn * 128 + c8));
                wv1[u] = __builtin_nontemporal_load((const u4v*)(wb + (size_t)nn * 128 + c8 + 4));
            }
#pragma unroll
            for (int u = 0; u < 4; ++u) {
                int nn = (gb * 4 + u) * 16 + rb;
                ushort4 p0, p1;
                float xe;
                xe = b2f((ushort)xv[u][0]);
                p0.x = f2b(fmaf((xe - mu) * rs, b2f((ushort)(wv0[u].x & 0xffffu)), b2f((ushort)(wv0[u].x >> 16))));
                xe = b2f((ushort)xv[u][1]);
                p0.y = f2b(fmaf((xe - mu) * rs, b2f((ushort)(wv0[u].y & 0xffffu)), b2f((ushort)(wv0[u].y >> 16))));
                xe = b2f((ushort)xv[u][2]);
                p0.z = f2b(fmaf((xe - mu) * rs, b2f((ushort)(wv0[u].z & 0xffffu)), b2f((ushort)(wv0[u].z >> 16))));
                xe = b2f((ushort)xv[u][3]);
                p0.w = f2b(fmaf((xe - mu) * rs, b2f((ushort)(wv0[u].w & 0xffffu)), b2f((ushort)(wv0[u].w >> 16))));
                xe = b2f((ushort)xv[u][4]);
                p1.x = f2b(fmaf((xe - mu) * rs, b2f((ushort)(wv1[u].x & 0xffffu)), b2f((ushort)(wv1[u].x >> 16))));
                xe = b2f((ushort)xv[u][5]);
                p1.y = f2b(fmaf((xe - mu) * rs, b2f((ushort)(wv1[u].y & 0xffffu)), b2f((ushort)(wv1[u].y >> 16))));
                xe = b2f((ushort)xv[u][6]);
                p1.z = f2b(fmaf((xe - mu) * rs, b2f((ushort)(wv1[u].z & 0xffffu)), b2f((ushort)(wv1[u].z >> 16))));
                xe = b2f((ushort)xv[u][7]);
                p1.w = f2b(fmaf((xe - mu) * rs, b2f((ushort)(wv1[u].w & 0xffffu)), b2f((ushort)(wv1[u].w >> 16))));
                *(ushort4*)&xT[swz4(nn, c8)] = p0;
                *(ushort4*)&xT[swz4(nn, c8 + 4)] = p1;
            }
        }
    }
    const int orow = wave * 32 + r;
    // prefetch GEMM1 A-slice for os=0 (8 independent loads), overlaps barrier
    s8b a1[8];
    {
        const ushort* w1p = w1b + (size_t)orow * 128 + q * 8;
#pragma unroll
        for (int m = 0; m < 2; ++m)
#pragma unroll
            for (int kk = 0; kk < 4; ++kk)
                a1[m * 4 + kk] = *(const s8b*)(w1p + m * 16 * 128 + kk * 32);
    }
    __syncthreads();
    // acc2 initialized with b2 (bias folded into MFMA C-in)
    float4 b2q0 = *(const float4*)&b2v[wave * 32 + q * 4];
    float4 b2q1 = *(const float4*)&b2v[wave * 32 + 16 + q * 4];
    f4 acc2[2][8];
#pragma unroll
    for (int j = 0; j < 8; ++j) {
        acc2[0][j] = (f4){b2q0.x, b2q0.y, b2q0.z, b2q0.w};
        acc2[1][j] = (f4){b2q1.x, b2q1.y, b2q1.z, b2q1.w};
    }

    for (int os = 0; os < 4; ++os) {
        // ---- GEMM1: h[os-slice rows owned by wave] = W1 x1 + b1 (b1 in C-in) ----
        float4 b1q0 = *(const float4*)&b1v[os * 128 + wave * 32 + q * 4];
        float4 b1q1 = *(const float4*)&b1v[os * 128 + wave * 32 + 16 + q * 4];
        f4 acc1[2][8];
#pragma unroll
        for (int j = 0; j < 8; ++j) {
            acc1[0][j] = (f4){b1q0.x, b1q0.y, b1q0.z, b1q0.w};
            acc1[1][j] = (f4){b1q1.x, b1q1.y, b1q1.z, b1q1.w};
        }
#pragma unroll
        for (int kk = 0; kk < 4; ++kk) {
            const int c0 = kk * 32 + q * 8;
#pragma unroll
            for (int j = 0; j < 8; ++j) {
                s8b bx = *(const s8b*)&xT[swz8(j * 16 + r, c0)];
                acc1[0][j] = __builtin_amdgcn_mfma_f32_16x16x32_bf16(a1[kk],     bx, acc1[0][j], 0, 0, 0);
                acc1[1][j] = __builtin_amdgcn_mfma_f32_16x16x32_bf16(a1[4 + kk], bx, acc1[1][j], 0, 0, 0);
            }
        }
        // prefetch GEMM2 A-slice for this os (independent of hT)
        s8b a2[8];
        {
            const ushort* w2p = w2b + (size_t)orow * 512 + os * 128 + q * 8;
#pragma unroll
            for (int m = 0; m < 2; ++m)
#pragma unroll
                for (int kk = 0; kk < 4; ++kk)
                    a2[m * 4 + kk] = *(const s8b*)(w2p + m * 16 * 512 + kk * 32);
        }
        // ---- gelu -> hT (cross-wave) ----
#pragma unroll
        for (int m = 0; m < 2; ++m) {
            const int hr0 = wave * 32 + m * 16 + q * 4;
#pragma unroll
            for (int j = 0; j < 8; ++j) {
                ushort4 pk;
                pk.x = f2b(gelu_f(acc1[m][j][0]));
                pk.y = f2b(gelu_f(acc1[m][j][1]));
                pk.z = f2b(gelu_f(acc1[m][j][2]));
                pk.w = f2b(gelu_f(acc1[m][j][3]));
                *(ushort4*)&hT[swz4(j * 16 + r, hr0)] = pk;
            }
        }
        __syncthreads();   // hT complete across waves
        // ---- GEMM2: acc2 += W2[:, os-slice] h ----
#pragma unroll
        for (int kk = 0; kk < 4; ++kk) {
            const int c0 = kk * 32 + q * 8;
#pragma unroll
            for (int j = 0; j < 8; ++j) {
                s8b hx = *(const s8b*)&hT[swz8(j * 16 + r, c0)];
                acc2[0][j] = __builtin_amdgcn_mfma_f32_16x16x32_bf16(a2[kk],     hx, acc2[0][j], 0, 0, 0);
                acc2[1][j] = __builtin_amdgcn_mfma_f32_16x16x32_bf16(a2[4 + kk], hx, acc2[1][j], 0, 0, 0);
            }
        }
        // prefetch next os's GEMM1 A-slice (overlaps barrier drain)
        if (os < 3) {
            const ushort* w1p = w1b + (size_t)((os + 1) * 128 + orow) * 128 + q * 8;
#pragma unroll
            for (int m = 0; m < 2; ++m)
#pragma unroll
                for (int kk = 0; kk < 4; ++kk)
                    a1[m * 4 + kk] = *(const s8b*)(w1p + m * 16 * 128 + kk * 32);
        }
        __syncthreads();   // hT consumed; safe to overwrite next os
    }
    // ---- epilogue: residual (b2 already in acc2), normal strided store, LN2 stats ----
    float s = 0.f, sq = 0.f;
#pragma unroll
    for (int m = 0; m < 2; ++m) {
        const int o0 = wave * 32 + m * 16 + q * 4;
#pragma unroll
        for (int j = 0; j < 8; ++j) {
            const int nn = j * 16 + r;
            ushort4 xr = *(const ushort4*)&xT[swz4(nn, o0)];
            float v0 = acc2[m][j][0] + b2f(xr.x);
            float v1 = acc2[m][j][1] + b2f(xr.y);
            float v2 = acc2[m][j][2] + b2f(xr.z);
            float v3 = acc2[m][j][3] + b2f(xr.w);
            float* op = xout + (size_t)b * DS + n0 + nn;
            op[(size_t)(o0 + 0) * N_SP] = v0;
            op[(size_t)(o0 + 1) * N_SP] = v1;
            op[(size_t)(o0 + 2) * N_SP] = v2;
            op[(size_t)(o0 + 3) * N_SP] = v3;
            s += (v0 + v1) + (v2 + v3);
            sq = fmaf(v0, v0, sq); sq = fmaf(v1, v1, sq);
            sq = fmaf(v2, v2, sq); sq = fmaf(v3, v3, sq);
        }
    }
#pragma unroll
    for (int off = 32; off > 0; off >>= 1) {
        s += __shfl_down(s, off, 64);
        sq += __shfl_down(sq, off, 64);
    }
    if (lane == 0) {
        atomicAdd(&st[32 + b], s);
        atomicAdd(&st[40 + b], sq);
    }
}

extern "C" void kernel_launch(void* const* d_in, const int* in_sizes, int n_in,
                              void* d_out, int out_size, void* d_ws, size_t ws_size,
                              hipStream_t stream) {
    const float* x      = (const float*)d_in[0];
    const float* qkv_w  = (const float*)d_in[1];
    const float* proj_w = (const float*)d_in[2];
    const float* proj_b = (const float*)d_in[3];
    const float* ln1_w  = (const float*)d_in[4];
    const float* ln1_b  = (const float*)d_in[5];
    const float* ln2_w  = (const float*)d_in[6];
    const float* ln2_b  = (const float*)d_in[7];
    const float* mlp_w1 = (const float*)d_in[8];
    const float* mlp_b1 = (const float*)d_in[9];
    const float* mlp_w2 = (const float*)d_in[10];
    const float* mlp_b2 = (const float*)d_in[11];
    float* out = (float*)d_out;

    char* wsb = (char*)d_ws;
    // small persistent region
    float*  st    = (float*)wsb;                      // 256 B
    float*  attn  = (float*)(wsb + 256);              // 65,536
    float*  PT    = (float*)(wsb + 65792);            // 65,536
    ushort* Mbb   = (ushort*)(wsb + 131328);          // 262,144
    ushort* w1b   = (ushort*)(wsb + 393472);          // 131,072
    ushort* w2b   = (ushort*)(wsb + 524544);          // 131,072
    float*  G     = (float*)(wsb + 655616);           // 524,288
    uint*   lnwbT = (uint*)(wsb + 1179904);           // 16,777,216
    // big dual-use region (stream-ordered lifetimes):
    //   Gpart (33.5MB, dead after k_greduce) -> x1Tb bf16 (67MB, dead after k_mlp)
    float*  Gpart = (float*)(wsb + 18874368);         // 33,554,432
    ushort* x1Tb  = (ushort*)(wsb + 18874368);        // 67,108,864

    hipMemsetAsync(st, 0, 64 * sizeof(float), stream);

    k_prep<<<1088, 256, 0, stream>>>(proj_w, PT, mlp_w1, w1b, mlp_w2, w2b,
                                     ln1_w, ln1_b, lnwbT);

    k_cov<<<dim3(64, 8), 256, 0, stream>>>(x, Gpart);
    k_greduce<<<512, 256, 0, stream>>>(Gpart, G);
    k_gram_small<<<64, 256, 0, stream>>>(G, qkv_w, attn);
    k_mfold<<<dim3(4, 8), 256, 0, stream>>>(attn, qkv_w, PT, Mbb);

    k_attnproj<<<dim3(256, 8), 256, 0, stream>>>(x, Mbb, proj_b, x1Tb, st);
    k_mlp<<<dim3(256, 8), 256, 0, stream>>>(x1Tb, out, w1b, mlp_b1, w2b, mlp_b2,
                                            lnwbT, st);
    k_lnapply<<<32768, 256, 0, stream>>>(out, ln2_w, ln2_b, st, out);
}

// Round 12
// 869.133 us; speedup vs baseline: 1.4909x; 1.0216x over previous
//
#include <hip/hip_runtime.h>
#include <hip/hip_bf16.h>
#include <math.h>

// TransformerBlock3D: B=8, C=128, S=32 (N=32768), HEADS=8 (dim_head=16), MLP=512
// Round 16: memory-level-parallelism round. Model: BW = outstanding/latency;
// R8 won by batching (more outstanding), R13/14 flat because waves doubled but
// loads/wave halved (product invariant). Raise the product within reg budget:
//  - k_cov/k_attnproj: launch_bounds caps (128/170 regs) were squeezing the
//    allocator though both are grid-limited to 2-3 blocks/CU -> (256,2), and
//    staging merged to one 16-load batch.
//  - k_mlp: staging one 24-load batch (was 2x12); a2 prefetch moved before
//    GEMM1 (in flight 2x longer); next-a1 issued right after GEMM1.
// Math: G=XX^T, attn=softmax(0.25*WqGWk^T), Mb=P.blockdiag(attn).Wv (bf16),
//       x1pre = Mb x + proj_b + x; x1 = LN1(x1pre); x2pre = x1 + b2 + W2 gelu(W1 x1 + b1).

#define N_SP 32768
typedef __hip_bfloat16 bf16;
static const size_t DS = (size_t)128 * N_SP;

typedef __attribute__((ext_vector_type(8))) short s8b;
typedef __attribute__((ext_vector_type(4))) float f4;
typedef __attribute__((ext_vector_type(4))) uint u4v;
typedef __attribute__((ext_vector_type(4))) ushort us4v;

__device__ __forceinline__ ushort f2b(float f) {
    __hip_bfloat16 h = __float2bfloat16(f);
    return *reinterpret_cast<ushort*>(&h);
}
__device__ __forceinline__ float b2f(ushort u) {
    unsigned v = ((unsigned)u) << 16;
    float f;
    __builtin_memcpy(&f, &v, 4);
    return f;
}
__device__ __forceinline__ float gelu_f(float h) {
    float u = 1.5957691216057308f * h * fmaf(0.044715f, h * h, 1.0f);
    float e = __expf(u);
    return h * (1.0f - __builtin_amdgcn_rcpf(e + 1.0f));
}
// LN stats from raw sums (identical arithmetic to the old k_finalize)
__device__ __forceinline__ void ln_stats(const float* st, int off, int b,
                                         float& mu, float& rs) {
    const float invn = 1.0f / 4194304.0f;
    mu = st[off + b] * invn;
    float var = st[off + 8 + b] * invn - mu * mu;
    rs = rsqrtf(var + 1e-5f);
}
// swizzled index for 128-col bf16 LDS tiles (c0 multiple of 8)
__device__ __forceinline__ int swz8(int n, int c0) {
    return n * 128 + (c0 ^ ((n & 15) << 3));
}
// swizzled index, c0 multiple of 4
__device__ __forceinline__ int swz4(int n, int c0) {
    return n * 128 + (((c0 & 0x78) ^ ((n & 15) << 3)) | (c0 & 4));
}

// ---------- merged prep: packln (512 blocks) | transpose (64) | cvt w1 (256) | cvt w2 (256) ----------
__global__ __launch_bounds__(256) void k_prep(const float* __restrict__ proj_w,
                                              float* __restrict__ PT,
                                              const float* __restrict__ mlp_w1,
                                              ushort* __restrict__ w1b,
                                              const float* __restrict__ mlp_w2,
                                              ushort* __restrict__ w2b,
                                              const float* __restrict__ ln1w,
                                              const float* __restrict__ ln1b,
                                              uint* __restrict__ lnwbT) {
    __shared__ uint tile[64 * 128];
    const int bx = blockIdx.x, t = threadIdx.x;
    if (bx < 512) {
        const int n0 = bx * 64;
        {
            const int c = t >> 1, nh = (t & 1) * 32;
            const float* wp = ln1w + (size_t)c * N_SP + n0 + nh;
            const float* bp = ln1b + (size_t)c * N_SP + n0 + nh;
#pragma unroll
            for (int g = 0; g < 8; ++g) {
                f4 wv = __builtin_nontemporal_load((const f4*)(wp + g * 4));
                f4 bv = __builtin_nontemporal_load((const f4*)(bp + g * 4));
                tile[(nh + g * 4 + 0) * 128 + c] = (uint)f2b(wv.x) | ((uint)f2b(bv.x) << 16);
                tile[(nh + g * 4 + 1) * 128 + c] = (uint)f2b(wv.y) | ((uint)f2b(bv.y) << 16);
                tile[(nh + g * 4 + 2) * 128 + c] = (uint)f2b(wv.z) | ((uint)f2b(bv.z) << 16);
                tile[(nh + g * 4 + 3) * 128 + c] = (uint)f2b(wv.w) | ((uint)f2b(bv.w) << 16);
            }
        }
        __syncthreads();
        uint* op = lnwbT + (size_t)n0 * 128;
#pragma unroll
        for (int g = 0; g < 8; ++g) {
            int idx = g * 256 + t;
            *(uint4*)(op + idx * 4) = *(const uint4*)&tile[idx * 4];
        }
    } else if (bx < 576) {
        int idx = (bx - 512) * 256 + t;
        int r = idx >> 7, c = idx & 127;
        PT[c * 128 + r] = proj_w[idx];
    } else if (bx < 832) {
        int i = (bx - 576) * 256 + t;
        w1b[i] = f2b(mlp_w1[i]);
    } else {
        int i = (bx - 832) * 256 + t;
        w2b[i] = f2b(mlp_w2[i]);
    }
}

// ---------- covariance partials via MFMA: Gpart[b*64+kb] = X Xs^T over 512 n ----------
// (256,2): grid-limited to 2 blocks/CU anyway; the old (256,4) cap (128 regs)
// was squeezing the allocator. Staging: single 16-load batch.
__global__ __launch_bounds__(256, 2) void k_cov(const float* __restrict__ x,
                                                float* __restrict__ Gpart) {
    __shared__ ushort xs[128 * 136];   // [c][n_local], pad 136 (16B-aligned rows)
    const int kb = blockIdx.x, b = blockIdx.y;
    const int t = threadIdx.x;
    const int wave = t >> 6, lane = t & 63, q = lane >> 4, r = lane & 15;
    f4 acc[8][2];
#pragma unroll
    for (int m = 0; m < 8; ++m) { acc[m][0] = (f4){0,0,0,0}; acc[m][1] = (f4){0,0,0,0}; }
    for (int ch = 0; ch < 4; ++ch) {
        const int nbase = kb * 512 + ch * 128;
        __syncthreads();
        {
            // nt float4-over-n staging, 16 loads in one batch
            const int nq = t & 31, cr = t >> 5;      // 32 n-quads, 8 c-rows
            const float* xp = x + (size_t)b * DS + nbase + nq * 4;
            f4 xv[16];
#pragma unroll
            for (int cc = 0; cc < 16; ++cc)
                xv[cc] = __builtin_nontemporal_load(
                    (const f4*)(xp + (size_t)(cr * 16 + cc) * N_SP));
#pragma unroll
            for (int cc = 0; cc < 16; ++cc) {
                int c = cr * 16 + cc;
                ushort4 pk;
                pk.x = f2b(xv[cc].x); pk.y = f2b(xv[cc].y);
                pk.z = f2b(xv[cc].z); pk.w = f2b(xv[cc].w);
                *(ushort4*)&xs[c * 136 + nq * 4] = pk;
            }
        }
        __syncthreads();
        for (int kk = 0; kk < 4; ++kk) {
            const int c0 = kk * 32 + q * 8;
            s8b bj0 = *(const s8b*)&xs[(wave * 32 + r) * 136 + c0];
            s8b bj1 = *(const s8b*)&xs[(wave * 32 + 16 + r) * 136 + c0];
#pragma unroll
            for (int m = 0; m < 8; ++m) {
                s8b a = *(const s8b*)&xs[(m * 16 + r) * 136 + c0];
                acc[m][0] = __builtin_amdgcn_mfma_f32_16x16x32_bf16(a, bj0, acc[m][0], 0, 0, 0);
                acc[m][1] = __builtin_amdgcn_mfma_f32_16x16x32_bf16(a, bj1, acc[m][1], 0, 0, 0);
            }
        }
    }
    float* gp = Gpart + ((size_t)b * 64 + kb) * 16384;
#pragma unroll
    for (int n2 = 0; n2 < 2; ++n2)
#pragma unroll
        for (int m = 0; m < 8; ++m)
#pragma unroll
            for (int rg = 0; rg < 4; ++rg) {
                int i = m * 16 + q * 4 + rg;
                int j = wave * 32 + n2 * 16 + r;
                gp[i * 128 + j] = acc[m][n2][rg];
            }
}

__global__ __launch_bounds__(256) void k_greduce(const float* __restrict__ Gpart,
                                                 float* __restrict__ G) {
    int tid = blockIdx.x * 256 + threadIdx.x;
    int b = tid >> 14, ij = tid & 16383;
    float s = 0.f;
#pragma unroll 8
    for (int kb = 0; kb < 64; ++kb)
        s += __builtin_nontemporal_load(&Gpart[((size_t)b * 64 + kb) * 16384 + ij]);
    G[tid] = s;
}

// ---------- gram + softmax ----------
__global__ __launch_bounds__(256) void k_gram_small(const float* __restrict__ G,
                                                    const float* __restrict__ qkv_w,
                                                    float* __restrict__ attn) {
    __shared__ float t1[16 * 132];
    __shared__ float sg[16 * 16];
    const int bh = blockIdx.x;
    const int b = bh >> 3, h = bh & 7;
    const int t = threadIdx.x;
    {
        const int i = t >> 4, c20 = (t & 15) * 8;
        const float* wq = qkv_w + (size_t)(h * 16 + i) * 128;
        const float* Gb = G + (size_t)b * 16384;
        float a[8];
#pragma unroll
        for (int k = 0; k < 8; ++k) a[k] = 0.f;
        for (int c = 0; c < 128; ++c) {
            float w = wq[c];
            const float* grow = Gb + c * 128 + c20;
#pragma unroll
            for (int k = 0; k < 8; ++k) a[k] = fmaf(w, grow[k], a[k]);
        }
#pragma unroll
        for (int k = 0; k < 8; ++k) t1[i * 132 + c20 + k] = a[k];
    }
    __syncthreads();
    {
        const int i = t >> 4, j = t & 15;
        const float* wk = qkv_w + (size_t)(128 + h * 16 + j) * 128;
        float s = 0.f;
        for (int c2 = 0; c2 < 128; ++c2) s = fmaf(t1[i * 132 + c2], wk[c2], s);
        sg[i * 16 + j] = s * 0.25f;
    }
    __syncthreads();
    if (t < 16) {
        float mx = -1e30f;
#pragma unroll
        for (int j = 0; j < 16; ++j) mx = fmaxf(mx, sg[t * 16 + j]);
        float e[16], sum = 0.f;
#pragma unroll
        for (int j = 0; j < 16; ++j) { e[j] = expf(sg[t * 16 + j] - mx); sum += e[j]; }
        float inv = 1.0f / sum;
#pragma unroll
        for (int j = 0; j < 16; ++j)
            attn[((size_t)bh * 16 + t) * 16 + j] = e[j] * inv;
    }
}

// ---------- fold: Mbb[b][o][c] = bf16( (P . blockdiag(attn) . Wv)[o][c] ) ----------
__global__ __launch_bounds__(256, 2) void k_mfold(const float* __restrict__ attn,
                                                  const float* __restrict__ qkv_w,
                                                  const float* __restrict__ PT,
                                                  ushort* __restrict__ Mbb) {
    __shared__ float t2[128 * 33];       // S[ci][c-slice of 32], pad 33
    const int c0b = blockIdx.x * 32;
    const int b = blockIdx.y;
    const int t = threadIdx.x;
    {
        const int hi = t & 127, cg2 = (t >> 7) * 16;
        const int h = hi >> 4;
        const float* at = attn + ((size_t)b * 128 + hi) * 16;
        float a[16];
#pragma unroll
        for (int j = 0; j < 16; ++j) a[j] = at[j];
        float sc[16];
#pragma unroll
        for (int c = 0; c < 16; ++c) sc[c] = 0.f;
        for (int j = 0; j < 16; ++j) {
            const float* wv = qkv_w + (size_t)(256 + h * 16 + j) * 128 + c0b + cg2;
            float aj = a[j];
#pragma unroll
            for (int c = 0; c < 16; ++c) sc[c] = fmaf(aj, wv[c], sc[c]);
        }
#pragma unroll
        for (int c = 0; c < 16; ++c) t2[hi * 33 + cg2 + c] = sc[c];
    }
    __syncthreads();
    const int cl = t & 31, og = t >> 5;
    float acc[16];
#pragma unroll
    for (int o = 0; o < 16; ++o) acc[o] = 0.f;
    for (int ci = 0; ci < 128; ++ci) {
        float s = t2[ci * 33 + cl];
        const float* pt = PT + ci * 128 + og * 16;
#pragma unroll
        for (int o = 0; o < 16; ++o) acc[o] = fmaf(pt[o], s, acc[o]);
    }
    ushort* m = Mbb + (size_t)b * 16384;
#pragma unroll
    for (int o = 0; o < 16; ++o)
        m[(size_t)(og * 16 + o) * 128 + c0b + cl] = f2b(acc[o]);
}

// ---------- attnproj: x1pre = Mb x + proj_b + x -> x1Tb[b][n][c] bf16, LN1 stats ----------
// (256,2): removes the 170-reg squeeze; staging one 16-load batch (2x depth).
__global__ __launch_bounds__(256, 2) void k_attnproj(const float* __restrict__ x,
                                                     const ushort* __restrict__ Mbb,
                                                     const float* __restrict__ proj_b,
                                                     ushort* __restrict__ x1Tb,
                                                     float* __restrict__ st) {
    __shared__ ushort xT[128 * 136];   // [n][c] bf16, pad 136
    const int b = blockIdx.y;
    const int n0 = blockIdx.x * 128;
    const int t = threadIdx.x;
    const int wave = t >> 6, lane = t & 63, q = lane >> 4, r = lane & 15;
    {
        const int nq = (t & 31) * 4;                 // 32 n-quads cover 128 n
        const int cg = (t >> 5) * 4;                 // 8 c-quads base
        const float* xb = x + (size_t)b * DS + n0 + nq;
        f4 xv[16];
#pragma unroll
        for (int u = 0; u < 16; ++u) {
            int c = (u >> 3) * 64 + cg + ((u >> 2) & 1) * 32 + (u & 3);
            xv[u] = __builtin_nontemporal_load((const f4*)(xb + (size_t)c * N_SP));
        }
#pragma unroll
        for (int u4 = 0; u4 < 4; ++u4) {
            int c0 = (u4 >> 1) * 64 + cg + (u4 & 1) * 32;
#pragma unroll
            for (int i = 0; i < 4; ++i) {
                us4v pk = { f2b(xv[u4 * 4 + 0][i]), f2b(xv[u4 * 4 + 1][i]),
                            f2b(xv[u4 * 4 + 2][i]), f2b(xv[u4 * 4 + 3][i]) };
                *(us4v*)&xT[(nq + i) * 136 + c0] = pk;
            }
        }
    }
    const int orow = wave * 32 + r;
    // prefetch the wave's Mb slice: 8 independent loads (overlaps barrier)
    s8b a[8];
    {
        const ushort* mp = Mbb + (size_t)b * 16384 + (size_t)orow * 128 + q * 8;
#pragma unroll
        for (int m = 0; m < 2; ++m)
#pragma unroll
            for (int kk = 0; kk < 4; ++kk)
                a[m * 4 + kk] = *(const s8b*)(mp + m * 16 * 128 + kk * 32);
    }
    __syncthreads();
    f4 acc[2][8];
#pragma unroll
    for (int m = 0; m < 2; ++m)
#pragma unroll
        for (int j = 0; j < 8; ++j) acc[m][j] = (f4){0,0,0,0};
#pragma unroll
    for (int kk = 0; kk < 4; ++kk) {
        const int c0 = kk * 32 + q * 8;
#pragma unroll
        for (int j = 0; j < 8; ++j) {
            s8b bx = *(const s8b*)&xT[(j * 16 + r) * 136 + c0];
            acc[0][j] = __builtin_amdgcn_mfma_f32_16x16x32_bf16(a[kk],     bx, acc[0][j], 0, 0, 0);
            acc[1][j] = __builtin_amdgcn_mfma_f32_16x16x32_bf16(a[4 + kk], bx, acc[1][j], 0, 0, 0);
        }
    }
    float s = 0.f, sq = 0.f;
    float4 pbq0 = *(const float4*)&proj_b[wave * 32 + q * 4];
    float4 pbq1 = *(const float4*)&proj_b[wave * 32 + 16 + q * 4];
    // j-outer/m-inner: both 8B halves of each 64B x1Tb line stored adjacently
#pragma unroll
    for (int j = 0; j < 8; ++j) {
        const int nn = j * 16 + r;
        ushort* obase = x1Tb + (size_t)b * DS + (size_t)(n0 + nn) * 128;
#pragma unroll
        for (int m = 0; m < 2; ++m) {
            const int o0 = wave * 32 + m * 16 + q * 4;
            const float4 pb = m ? pbq1 : pbq0;
            ushort4 xr = *(const ushort4*)&xT[nn * 136 + o0];
            float v0 = acc[m][j][0] + pb.x + b2f(xr.x);
            float v1 = acc[m][j][1] + pb.y + b2f(xr.y);
            float v2 = acc[m][j][2] + pb.z + b2f(xr.z);
            float v3 = acc[m][j][3] + pb.w + b2f(xr.w);
            us4v ov = { f2b(v0), f2b(v1), f2b(v2), f2b(v3) };
            __builtin_nontemporal_store(ov, (us4v*)(obase + o0));
            s += (v0 + v1) + (v2 + v3);
            sq = fmaf(v0, v0, sq); sq = fmaf(v1, v1, sq);
            sq = fmaf(v2, v2, sq); sq = fmaf(v3, v3, sq);
        }
    }
#pragma unroll
    for (int off = 32; off > 0; off >>= 1) {
        s += __shfl_down(s, off, 64);
        sq += __shfl_down(sq, off, 64);
    }
    if (lane == 0) {
        atomicAdd(&st[0 + b], s);
        atomicAdd(&st[8 + b], sq);
    }
}

// ---------- LN2 apply, direct f32 params; stats inline from raw sums ----------
__global__ __launch_bounds__(256) void k_lnapply(const float* __restrict__ in,
                                                 const float* __restrict__ lnw,
                                                 const float* __restrict__ lnb,
                                                 const float* __restrict__ st,
                                                 float* __restrict__ out) {
    size_t i4 = (size_t)blockIdx.x * 256 + threadIdx.x;
    int b = (int)(i4 >> 20);
    size_t cn = i4 * 4 - (size_t)b * 4194304;
    float mu, rs;
    ln_stats(st, 32, b, mu, rs);
    const float4 xv = *(const float4*)(in + (size_t)b * DS + cn);
    const float4 wv = *(const float4*)(lnw + cn);
    const float4 bv = *(const float4*)(lnb + cn);
    float4 o;
    o.x = fmaf((xv.x - mu) * rs, wv.x, bv.x);
    o.y = fmaf((xv.y - mu) * rs, wv.y, bv.y);
    o.z = fmaf((xv.z - mu) * rs, wv.z, bv.z);
    o.w = fmaf((xv.w - mu) * rs, wv.w, bv.w);
    *(float4*)(out + (size_t)b * DS + cn) = o;
}

// ---------- fused LN1-apply + MLP + residual + LN2 stats, 128-n tile ----------
// Staging: one 24-load batch. a2 prefetched BEFORE GEMM1; next-a1 right after.
__global__ __launch_bounds__(256, 2) void k_mlp(const ushort* __restrict__ x1Tb,
                                                float* __restrict__ xout,
                                                const ushort* __restrict__ w1b,
                                                const float* __restrict__ b1v,
                                                const ushort* __restrict__ w2b,
                                                const float* __restrict__ b2v,
                                                const uint* __restrict__ lnwbT,
                                                float* __restrict__ st) {
    __shared__ ushort xT[128 * 128];   // swizzled, x1 = LN1(x1pre) bf16
    __shared__ ushort hT[128 * 128];   // swizzled, gelu os-slice [n][hr] bf16
    const int b = blockIdx.y;
    const int n0 = blockIdx.x * 128;
    const int t = threadIdx.x;
    const int wave = t >> 6, lane = t & 63, q = lane >> 4, r = lane & 15;
    float mu, rs;
    ln_stats(st, 0, b, mu, rs);
    {
        // 16 col-groups of 8 c x 16 rows; ONE batch of 24 nt loads in flight
        const int c8 = (t & 15) * 8, rb = t >> 4;
        const ushort* xb = x1Tb + (size_t)b * DS + (size_t)n0 * 128;
        const uint*  wb = lnwbT + (size_t)n0 * 128;
        s8b xv[8]; u4v wv0[8], wv1[8];
#pragma unroll
        for (int u = 0; u < 8; ++u) {
            int nn = u * 16 + rb;
            xv[u]  = __builtin_nontemporal_load((const s8b*)(xb + (size_t)nn * 128 + c8));
            wv0[u] = __builtin_nontemporal_load((const u4v*)(wb + (size_t)nn * 128 + c8));
            wv1[u] = __builtin_nontemporal_load((const u4v*)(wb + (size_t)nn * 128 + c8 + 4));
        }
#pragma unroll
        for (int u = 0; u < 8; ++u) {
            int nn = u * 16 + rb;
            ushort4 p0, p1;
            float xe;
            xe = b2f((ushort)xv[u][0]);
            p0.x = f2b(fmaf((xe - mu) * rs, b2f((ushort)(wv0[u].x & 0xffffu)), b2f((ushort)(wv0[u].x >> 16))));
            xe = b2f((ushort)xv[u][1]);
            p0.y = f2b(fmaf((xe - mu) * rs, b2f((ushort)(wv0[u].y & 0xffffu)), b2f((ushort)(wv0[u].y >> 16))));
            xe = b2f((ushort)xv[u][2]);
            p0.z = f2b(fmaf((xe - mu) * rs, b2f((ushort)(wv0[u].z & 0xffffu)), b2f((ushort)(wv0[u].z >> 16))));
            xe = b2f((ushort)xv[u][3]);
            p0.w = f2b(fmaf((xe - mu) * rs, b2f((ushort)(wv0[u].w & 0xffffu)), b2f((ushort)(wv0[u].w >> 16))));
            xe = b2f((ushort)xv[u][4]);
            p1.x = f2b(fmaf((xe - mu) * rs, b2f((ushort)(wv1[u].x & 0xffffu)), b2f((ushort)(wv1[u].x >> 16))));
            xe = b2f((ushort)xv[u][5]);
            p1.y = f2b(fmaf((xe - mu) * rs, b2f((ushort)(wv1[u].y & 0xffffu)), b2f((ushort)(wv1[u].y >> 16))));
            xe = b2f((ushort)xv[u][6]);
            p1.z = f2b(fmaf((xe - mu) * rs, b2f((ushort)(wv1[u].z & 0xffffu)), b2f((ushort)(wv1[u].z >> 16))));
            xe = b2f((ushort)xv[u][7]);
            p1.w = f2b(fmaf((xe - mu) * rs, b2f((ushort)(wv1[u].w & 0xffffu)), b2f((ushort)(wv1[u].w >> 16))));
            *(ushort4*)&xT[swz4(nn, c8)] = p0;
            *(ushort4*)&xT[swz4(nn, c8 + 4)] = p1;
        }
    }
    const int orow = wave * 32 + r;
    // prefetch GEMM1 A-slice for os=0 (8 independent loads), overlaps barrier
    s8b a1[8];
    {
        const ushort* w1p = w1b + (size_t)orow * 128 + q * 8;
#pragma unroll
        for (int m = 0; m < 2; ++m)
#pragma unroll
            for (int kk = 0; kk < 4; ++kk)
                a1[m * 4 + kk] = *(const s8b*)(w1p + m * 16 * 128 + kk * 32);
    }
    __syncthreads();
    // acc2 initialized with b2 (bias folded into MFMA C-in)
    float4 b2q0 = *(const float4*)&b2v[wave * 32 + q * 4];
    float4 b2q1 = *(const float4*)&b2v[wave * 32 + 16 + q * 4];
    f4 acc2[2][8];
#pragma unroll
    for (int j = 0; j < 8; ++j) {
        acc2[0][j] = (f4){b2q0.x, b2q0.y, b2q0.z, b2q0.w};
        acc2[1][j] = (f4){b2q1.x, b2q1.y, b2q1.z, b2q1.w};
    }

    for (int os = 0; os < 4; ++os) {
        // prefetch GEMM2 A-slice for this os FIRST (in flight through GEMM1+gelu)
        s8b a2[8];
        {
            const ushort* w2p = w2b + (size_t)orow * 512 + os * 128 + q * 8;
#pragma unroll
            for (int m = 0; m < 2; ++m)
#pragma unroll
                for (int kk = 0; kk < 4; ++kk)
                    a2[m * 4 + kk] = *(const s8b*)(w2p + m * 16 * 512 + kk * 32);
        }
        // ---- GEMM1: h[os-slice rows owned by wave] = W1 x1 + b1 (b1 in C-in) ----
        float4 b1q0 = *(const float4*)&b1v[os * 128 + wave * 32 + q * 4];
        float4 b1q1 = *(const float4*)&b1v[os * 128 + wave * 32 + 16 + q * 4];
        f4 acc1[2][8];
#pragma unroll
        for (int j = 0; j < 8; ++j) {
            acc1[0][j] = (f4){b1q0.x, b1q0.y, b1q0.z, b1q0.w};
            acc1[1][j] = (f4){b1q1.x, b1q1.y, b1q1.z, b1q1.w};
        }
#pragma unroll
        for (int kk = 0; kk < 4; ++kk) {
            const int c0 = kk * 32 + q * 8;
#pragma unroll
            for (int j = 0; j < 8; ++j) {
                s8b bx = *(const s8b*)&xT[swz8(j * 16 + r, c0)];
                acc1[0][j] = __builtin_amdgcn_mfma_f32_16x16x32_bf16(a1[kk],     bx, acc1[0][j], 0, 0, 0);
                acc1[1][j] = __builtin_amdgcn_mfma_f32_16x16x32_bf16(a1[4 + kk], bx, acc1[1][j], 0, 0, 0);
            }
        }
        // a1 free now: issue next os's GEMM1 A-slice (in flight through
        // gelu + barrier + GEMM2 + barrier)
        if (os < 3) {
            const ushort* w1p = w1b + (size_t)((os + 1) * 128 + orow) * 128 + q * 8;
#pragma unroll
            for (int m = 0; m < 2; ++m)
#pragma unroll
                for (int kk = 0; kk < 4; ++kk)
                    a1[m * 4 + kk] = *(const s8b*)(w1p + m * 16 * 128 + kk * 32);
        }
        // ---- gelu -> hT (cross-wave) ----
#pragma unroll
        for (int m = 0; m < 2; ++m) {
            const int hr0 = wave * 32 + m * 16 + q * 4;
#pragma unroll
            for (int j = 0; j < 8; ++j) {
                ushort4 pk;
                pk.x = f2b(gelu_f(acc1[m][j][0]));
                pk.y = f2b(gelu_f(acc1[m][j][1]));
                pk.z = f2b(gelu_f(acc1[m][j][2]));
                pk.w = f2b(gelu_f(acc1[m][j][3]));
                *(ushort4*)&hT[swz4(j * 16 + r, hr0)] = pk;
            }
        }
        __syncthreads();   // hT complete across waves
        // ---- GEMM2: acc2 += W2[:, os-slice] h ----
#pragma unroll
        for (int kk = 0; kk < 4; ++kk) {
            const int c0 = kk * 32 + q * 8;
#pragma unroll
            for (int j = 0; j < 8; ++j) {
                s8b hx = *(const s8b*)&hT[swz8(j * 16 + r, c0)];
                acc2[0][j] = __builtin_amdgcn_mfma_f32_16x16x32_bf16(a2[kk],     hx, acc2[0][j], 0, 0, 0);
                acc2[1][j] = __builtin_amdgcn_mfma_f32_16x16x32_bf16(a2[4 + kk], hx, acc2[1][j], 0, 0, 0);
            }
        }
        __syncthreads();   // hT consumed; safe to overwrite next os
    }
    // ---- epilogue: residual (b2 already in acc2), normal strided store, LN2 stats ----
    float s = 0.f, sq = 0.f;
#pragma unroll
    for (int m = 0; m < 2; ++m) {
        const int o0 = wave * 32 + m * 16 + q * 4;
#pragma unroll
        for (int j = 0; j < 8; ++j) {
            const int nn = j * 16 + r;
            ushort4 xr = *(const ushort4*)&xT[swz4(nn, o0)];
            float v0 = acc2[m][j][0] + b2f(xr.x);
            float v1 = acc2[m][j][1] + b2f(xr.y);
            float v2 = acc2[m][j][2] + b2f(xr.z);
            float v3 = acc2[m][j][3] + b2f(xr.w);
            float* op = xout + (size_t)b * DS + n0 + nn;
            op[(size_t)(o0 + 0) * N_SP] = v0;
            op[(size_t)(o0 + 1) * N_SP] = v1;
            op[(size_t)(o0 + 2) * N_SP] = v2;
            op[(size_t)(o0 + 3) * N_SP] = v3;
            s += (v0 + v1) + (v2 + v3);
            sq = fmaf(v0, v0, sq); sq = fmaf(v1, v1, sq);
            sq = fmaf(v2, v2, sq); sq = fmaf(v3, v3, sq);
        }
    }
#pragma unroll
    for (int off = 32; off > 0; off >>= 1) {
        s += __shfl_down(s, off, 64);
        sq += __shfl_down(sq, off, 64);
    }
    if (lane == 0) {
        atomicAdd(&st[32 + b], s);
        atomicAdd(&st[40 + b], sq);
    }
}

extern "C" void kernel_launch(void* const* d_in, const int* in_sizes, int n_in,
                              void* d_out, int out_size, void* d_ws, size_t ws_size,
                              hipStream_t stream) {
    const float* x      = (const float*)d_in[0];
    const float* qkv_w  = (const float*)d_in[1];
    const float* proj_w = (const float*)d_in[2];
    const float* proj_b = (const float*)d_in[3];
    const float* ln1_w  = (const float*)d_in[4];
    const float* ln1_b  = (const float*)d_in[5];
    const float* ln2_w  = (const float*)d_in[6];
    const float* ln2_b  = (const float*)d_in[7];
    const float* mlp_w1 = (const float*)d_in[8];
    const float* mlp_b1 = (const float*)d_in[9];
    const float* mlp_w2 = (const float*)d_in[10];
    const float* mlp_b2 = (const float*)d_in[11];
    float* out = (float*)d_out;

    char* wsb = (char*)d_ws;
    // small persistent region
    float*  st    = (float*)wsb;                      // 256 B
    float*  attn  = (float*)(wsb + 256);              // 65,536
    float*  PT    = (float*)(wsb + 65792);            // 65,536
    ushort* Mbb   = (ushort*)(wsb + 131328);          // 262,144
    ushort* w1b   = (ushort*)(wsb + 393472);          // 131,072
    ushort* w2b   = (ushort*)(wsb + 524544);          // 131,072
    float*  G     = (float*)(wsb + 655616);           // 524,288
    uint*   lnwbT = (uint*)(wsb + 1179904);           // 16,777,216
    // big dual-use region (stream-ordered lifetimes):
    //   Gpart (33.5MB, dead after k_greduce) -> x1Tb bf16 (67MB, dead after k_mlp)
    float*  Gpart = (float*)(wsb + 18874368);         // 33,554,432
    ushort* x1Tb  = (ushort*)(wsb + 18874368);        // 67,108,864

    hipMemsetAsync(st, 0, 64 * sizeof(float), stream);

    k_prep<<<1088, 256, 0, stream>>>(proj_w, PT, mlp_w1, w1b, mlp_w2, w2b,
                                     ln1_w, ln1_b, lnwbT);

    k_cov<<<dim3(64, 8), 256, 0, stream>>>(x, Gpart);
    k_greduce<<<512, 256, 0, stream>>>(Gpart, G);
    k_gram_small<<<64, 256, 0, stream>>>(G, qkv_w, attn);
    k_mfold<<<dim3(4, 8), 256, 0, stream>>>(attn, qkv_w, PT, Mbb);

    k_attnproj<<<dim3(256, 8), 256, 0, stream>>>(x, Mbb, proj_b, x1Tb, st);
    k_mlp<<<dim3(256, 8), 256, 0, stream>>>(x1Tb, out, w1b, mlp_b1, w2b, mlp_b2,
                                            lnwbT, st);
    k_lnapply<<<32768, 256, 0, stream>>>(out, ln2_w, ln2_b, st, out);
}

// Round 13
// 867.245 us; speedup vs baseline: 1.4942x; 1.0022x over previous
//
#include <hip/hip_runtime.h>
#include <hip/hip_bf16.h>
#include <math.h>

// TransformerBlock3D: B=8, C=128, S=32 (N=32768), HEADS=8 (dim_head=16), MLP=512
// Round 17: keep R16's winners (k_cov/k_attnproj (256,2) + deep staging batches,
// merged prep, inline LN stats), revert R16's loser: k_mlp back to the proven
// R15 schedule (270us: 2x12 staging, a1-prefetch->barrier, GEMM1, a2-prefetch,
// gelu, barrier, GEMM2, next-a1, barrier). R16's 24-load batch + a2-hoist
// stretched live ranges -> worse scheduling (VALUBusy 22.9->20.7, 297us).
// Math: G=XX^T, attn=softmax(0.25*WqGWk^T), Mb=P.blockdiag(attn).Wv (bf16),
//       x1pre = Mb x + proj_b + x; x1 = LN1(x1pre); x2pre = x1 + b2 + W2 gelu(W1 x1 + b1).

#define N_SP 32768
typedef __hip_bfloat16 bf16;
static const size_t DS = (size_t)128 * N_SP;

typedef __attribute__((ext_vector_type(8))) short s8b;
typedef __attribute__((ext_vector_type(4))) float f4;
typedef __attribute__((ext_vector_type(4))) uint u4v;
typedef __attribute__((ext_vector_type(4))) ushort us4v;

__device__ __forceinline__ ushort f2b(float f) {
    __hip_bfloat16 h = __float2bfloat16(f);
    return *reinterpret_cast<ushort*>(&h);
}
__device__ __forceinline__ float b2f(ushort u) {
    unsigned v = ((unsigned)u) << 16;
    float f;
    __builtin_memcpy(&f, &v, 4);
    return f;
}
__device__ __forceinline__ float gelu_f(float h) {
    float u = 1.5957691216057308f * h * fmaf(0.044715f, h * h, 1.0f);
    float e = __expf(u);
    return h * (1.0f - __builtin_amdgcn_rcpf(e + 1.0f));
}
// LN stats from raw sums (identical arithmetic to the old k_finalize)
__device__ __forceinline__ void ln_stats(const float* st, int off, int b,
                                         float& mu, float& rs) {
    const float invn = 1.0f / 4194304.0f;
    mu = st[off + b] * invn;
    float var = st[off + 8 + b] * invn - mu * mu;
    rs = rsqrtf(var + 1e-5f);
}
// swizzled index for 128-col bf16 LDS tiles (c0 multiple of 8)
__device__ __forceinline__ int swz8(int n, int c0) {
    return n * 128 + (c0 ^ ((n & 15) << 3));
}
// swizzled index, c0 multiple of 4
__device__ __forceinline__ int swz4(int n, int c0) {
    return n * 128 + (((c0 & 0x78) ^ ((n & 15) << 3)) | (c0 & 4));
}

// ---------- merged prep: packln (512 blocks) | transpose (64) | cvt w1 (256) | cvt w2 (256) ----------
__global__ __launch_bounds__(256) void k_prep(const float* __restrict__ proj_w,
                                              float* __restrict__ PT,
                                              const float* __restrict__ mlp_w1,
                                              ushort* __restrict__ w1b,
                                              const float* __restrict__ mlp_w2,
                                              ushort* __restrict__ w2b,
                                              const float* __restrict__ ln1w,
                                              const float* __restrict__ ln1b,
                                              uint* __restrict__ lnwbT) {
    __shared__ uint tile[64 * 128];
    const int bx = blockIdx.x, t = threadIdx.x;
    if (bx < 512) {
        const int n0 = bx * 64;
        {
            const int c = t >> 1, nh = (t & 1) * 32;
            const float* wp = ln1w + (size_t)c * N_SP + n0 + nh;
            const float* bp = ln1b + (size_t)c * N_SP + n0 + nh;
#pragma unroll
            for (int g = 0; g < 8; ++g) {
                f4 wv = __builtin_nontemporal_load((const f4*)(wp + g * 4));
                f4 bv = __builtin_nontemporal_load((const f4*)(bp + g * 4));
                tile[(nh + g * 4 + 0) * 128 + c] = (uint)f2b(wv.x) | ((uint)f2b(bv.x) << 16);
                tile[(nh + g * 4 + 1) * 128 + c] = (uint)f2b(wv.y) | ((uint)f2b(bv.y) << 16);
                tile[(nh + g * 4 + 2) * 128 + c] = (uint)f2b(wv.z) | ((uint)f2b(bv.z) << 16);
                tile[(nh + g * 4 + 3) * 128 + c] = (uint)f2b(wv.w) | ((uint)f2b(bv.w) << 16);
            }
        }
        __syncthreads();
        uint* op = lnwbT + (size_t)n0 * 128;
#pragma unroll
        for (int g = 0; g < 8; ++g) {
            int idx = g * 256 + t;
            *(uint4*)(op + idx * 4) = *(const uint4*)&tile[idx * 4];
        }
    } else if (bx < 576) {
        int idx = (bx - 512) * 256 + t;
        int r = idx >> 7, c = idx & 127;
        PT[c * 128 + r] = proj_w[idx];
    } else if (bx < 832) {
        int i = (bx - 576) * 256 + t;
        w1b[i] = f2b(mlp_w1[i]);
    } else {
        int i = (bx - 832) * 256 + t;
        w2b[i] = f2b(mlp_w2[i]);
    }
}

// ---------- covariance partials via MFMA: Gpart[b*64+kb] = X Xs^T over 512 n ----------
__global__ __launch_bounds__(256, 2) void k_cov(const float* __restrict__ x,
                                                float* __restrict__ Gpart) {
    __shared__ ushort xs[128 * 136];   // [c][n_local], pad 136 (16B-aligned rows)
    const int kb = blockIdx.x, b = blockIdx.y;
    const int t = threadIdx.x;
    const int wave = t >> 6, lane = t & 63, q = lane >> 4, r = lane & 15;
    f4 acc[8][2];
#pragma unroll
    for (int m = 0; m < 8; ++m) { acc[m][0] = (f4){0,0,0,0}; acc[m][1] = (f4){0,0,0,0}; }
    for (int ch = 0; ch < 4; ++ch) {
        const int nbase = kb * 512 + ch * 128;
        __syncthreads();
        {
            // nt float4-over-n staging, 16 loads in one batch
            const int nq = t & 31, cr = t >> 5;      // 32 n-quads, 8 c-rows
            const float* xp = x + (size_t)b * DS + nbase + nq * 4;
            f4 xv[16];
#pragma unroll
            for (int cc = 0; cc < 16; ++cc)
                xv[cc] = __builtin_nontemporal_load(
                    (const f4*)(xp + (size_t)(cr * 16 + cc) * N_SP));
#pragma unroll
            for (int cc = 0; cc < 16; ++cc) {
                int c = cr * 16 + cc;
                ushort4 pk;
                pk.x = f2b(xv[cc].x); pk.y = f2b(xv[cc].y);
                pk.z = f2b(xv[cc].z); pk.w = f2b(xv[cc].w);
                *(ushort4*)&xs[c * 136 + nq * 4] = pk;
            }
        }
        __syncthreads();
        for (int kk = 0; kk < 4; ++kk) {
            const int c0 = kk * 32 + q * 8;
            s8b bj0 = *(const s8b*)&xs[(wave * 32 + r) * 136 + c0];
            s8b bj1 = *(const s8b*)&xs[(wave * 32 + 16 + r) * 136 + c0];
#pragma unroll
            for (int m = 0; m < 8; ++m) {
                s8b a = *(const s8b*)&xs[(m * 16 + r) * 136 + c0];
                acc[m][0] = __builtin_amdgcn_mfma_f32_16x16x32_bf16(a, bj0, acc[m][0], 0, 0, 0);
                acc[m][1] = __builtin_amdgcn_mfma_f32_16x16x32_bf16(a, bj1, acc[m][1], 0, 0, 0);
            }
        }
    }
    float* gp = Gpart + ((size_t)b * 64 + kb) * 16384;
#pragma unroll
    for (int n2 = 0; n2 < 2; ++n2)
#pragma unroll
        for (int m = 0; m < 8; ++m)
#pragma unroll
            for (int rg = 0; rg < 4; ++rg) {
                int i = m * 16 + q * 4 + rg;
                int j = wave * 32 + n2 * 16 + r;
                gp[i * 128 + j] = acc[m][n2][rg];
            }
}

__global__ __launch_bounds__(256) void k_greduce(const float* __restrict__ Gpart,
                                                 float* __restrict__ G) {
    int tid = blockIdx.x * 256 + threadIdx.x;
    int b = tid >> 14, ij = tid & 16383;
    float s = 0.f;
#pragma unroll 8
    for (int kb = 0; kb < 64; ++kb)
        s += __builtin_nontemporal_load(&Gpart[((size_t)b * 64 + kb) * 16384 + ij]);
    G[tid] = s;
}

// ---------- gram + softmax ----------
__global__ __launch_bounds__(256) void k_gram_small(const float* __restrict__ G,
                                                    const float* __restrict__ qkv_w,
                                                    float* __restrict__ attn) {
    __shared__ float t1[16 * 132];
    __shared__ float sg[16 * 16];
    const int bh = blockIdx.x;
    const int b = bh >> 3, h = bh & 7;
    const int t = threadIdx.x;
    {
        const int i = t >> 4, c20 = (t & 15) * 8;
        const float* wq = qkv_w + (size_t)(h * 16 + i) * 128;
        const float* Gb = G + (size_t)b * 16384;
        float a[8];
#pragma unroll
        for (int k = 0; k < 8; ++k) a[k] = 0.f;
        for (int c = 0; c < 128; ++c) {
            float w = wq[c];
            const float* grow = Gb + c * 128 + c20;
#pragma unroll
            for (int k = 0; k < 8; ++k) a[k] = fmaf(w, grow[k], a[k]);
        }
#pragma unroll
        for (int k = 0; k < 8; ++k) t1[i * 132 + c20 + k] = a[k];
    }
    __syncthreads();
    {
        const int i = t >> 4, j = t & 15;
        const float* wk = qkv_w + (size_t)(128 + h * 16 + j) * 128;
        float s = 0.f;
        for (int c2 = 0; c2 < 128; ++c2) s = fmaf(t1[i * 132 + c2], wk[c2], s);
        sg[i * 16 + j] = s * 0.25f;
    }
    __syncthreads();
    if (t < 16) {
        float mx = -1e30f;
#pragma unroll
        for (int j = 0; j < 16; ++j) mx = fmaxf(mx, sg[t * 16 + j]);
        float e[16], sum = 0.f;
#pragma unroll
        for (int j = 0; j < 16; ++j) { e[j] = expf(sg[t * 16 + j] - mx); sum += e[j]; }
        float inv = 1.0f / sum;
#pragma unroll
        for (int j = 0; j < 16; ++j)
            attn[((size_t)bh * 16 + t) * 16 + j] = e[j] * inv;
    }
}

// ---------- fold: Mbb[b][o][c] = bf16( (P . blockdiag(attn) . Wv)[o][c] ) ----------
__global__ __launch_bounds__(256, 2) void k_mfold(const float* __restrict__ attn,
                                                  const float* __restrict__ qkv_w,
                                                  const float* __restrict__ PT,
                                                  ushort* __restrict__ Mbb) {
    __shared__ float t2[128 * 33];       // S[ci][c-slice of 32], pad 33
    const int c0b = blockIdx.x * 32;
    const int b = blockIdx.y;
    const int t = threadIdx.x;
    {
        const int hi = t & 127, cg2 = (t >> 7) * 16;
        const int h = hi >> 4;
        const float* at = attn + ((size_t)b * 128 + hi) * 16;
        float a[16];
#pragma unroll
        for (int j = 0; j < 16; ++j) a[j] = at[j];
        float sc[16];
#pragma unroll
        for (int c = 0; c < 16; ++c) sc[c] = 0.f;
        for (int j = 0; j < 16; ++j) {
            const float* wv = qkv_w + (size_t)(256 + h * 16 + j) * 128 + c0b + cg2;
            float aj = a[j];
#pragma unroll
            for (int c = 0; c < 16; ++c) sc[c] = fmaf(aj, wv[c], sc[c]);
        }
#pragma unroll
        for (int c = 0; c < 16; ++c) t2[hi * 33 + cg2 + c] = sc[c];
    }
    __syncthreads();
    const int cl = t & 31, og = t >> 5;
    float acc[16];
#pragma unroll
    for (int o = 0; o < 16; ++o) acc[o] = 0.f;
    for (int ci = 0; ci < 128; ++ci) {
        float s = t2[ci * 33 + cl];
        const float* pt = PT + ci * 128 + og * 16;
#pragma unroll
        for (int o = 0; o < 16; ++o) acc[o] = fmaf(pt[o], s, acc[o]);
    }
    ushort* m = Mbb + (size_t)b * 16384;
#pragma unroll
    for (int o = 0; o < 16; ++o)
        m[(size_t)(og * 16 + o) * 128 + c0b + cl] = f2b(acc[o]);
}

// ---------- attnproj: x1pre = Mb x + proj_b + x -> x1Tb[b][n][c] bf16, LN1 stats ----------
// (256,2); staging one 16-load batch + 4x4 reg transpose.
__global__ __launch_bounds__(256, 2) void k_attnproj(const float* __restrict__ x,
                                                     const ushort* __restrict__ Mbb,
                                                     const float* __restrict__ proj_b,
                                                     ushort* __restrict__ x1Tb,
                                                     float* __restrict__ st) {
    __shared__ ushort xT[128 * 136];   // [n][c] bf16, pad 136
    const int b = blockIdx.y;
    const int n0 = blockIdx.x * 128;
    const int t = threadIdx.x;
    const int wave = t >> 6, lane = t & 63, q = lane >> 4, r = lane & 15;
    {
        const int nq = (t & 31) * 4;                 // 32 n-quads cover 128 n
        const int cg = (t >> 5) * 4;                 // 8 c-quads base
        const float* xb = x + (size_t)b * DS + n0 + nq;
        f4 xv[16];
#pragma unroll
        for (int u = 0; u < 16; ++u) {
            int c = (u >> 3) * 64 + cg + ((u >> 2) & 1) * 32 + (u & 3);
            xv[u] = __builtin_nontemporal_load((const f4*)(xb + (size_t)c * N_SP));
        }
#pragma unroll
        for (int u4 = 0; u4 < 4; ++u4) {
            int c0 = (u4 >> 1) * 64 + cg + (u4 & 1) * 32;
#pragma unroll
            for (int i = 0; i < 4; ++i) {
                us4v pk = { f2b(xv[u4 * 4 + 0][i]), f2b(xv[u4 * 4 + 1][i]),
                            f2b(xv[u4 * 4 + 2][i]), f2b(xv[u4 * 4 + 3][i]) };
                *(us4v*)&xT[(nq + i) * 136 + c0] = pk;
            }
        }
    }
    const int orow = wave * 32 + r;
    // prefetch the wave's Mb slice: 8 independent loads (overlaps barrier)
    s8b a[8];
    {
        const ushort* mp = Mbb + (size_t)b * 16384 + (size_t)orow * 128 + q * 8;
#pragma unroll
        for (int m = 0; m < 2; ++m)
#pragma unroll
            for (int kk = 0; kk < 4; ++kk)
                a[m * 4 + kk] = *(const s8b*)(mp + m * 16 * 128 + kk * 32);
    }
    __syncthreads();
    f4 acc[2][8];
#pragma unroll
    for (int m = 0; m < 2; ++m)
#pragma unroll
        for (int j = 0; j < 8; ++j) acc[m][j] = (f4){0,0,0,0};
#pragma unroll
    for (int kk = 0; kk < 4; ++kk) {
        const int c0 = kk * 32 + q * 8;
#pragma unroll
        for (int j = 0; j < 8; ++j) {
            s8b bx = *(const s8b*)&xT[(j * 16 + r) * 136 + c0];
            acc[0][j] = __builtin_amdgcn_mfma_f32_16x16x32_bf16(a[kk],     bx, acc[0][j], 0, 0, 0);
            acc[1][j] = __builtin_amdgcn_mfma_f32_16x16x32_bf16(a[4 + kk], bx, acc[1][j], 0, 0, 0);
        }
    }
    float s = 0.f, sq = 0.f;
    float4 pbq0 = *(const float4*)&proj_b[wave * 32 + q * 4];
    float4 pbq1 = *(const float4*)&proj_b[wave * 32 + 16 + q * 4];
    // j-outer/m-inner: both 8B halves of each 64B x1Tb line stored adjacently
#pragma unroll
    for (int j = 0; j < 8; ++j) {
        const int nn = j * 16 + r;
        ushort* obase = x1Tb + (size_t)b * DS + (size_t)(n0 + nn) * 128;
#pragma unroll
        for (int m = 0; m < 2; ++m) {
            const int o0 = wave * 32 + m * 16 + q * 4;
            const float4 pb = m ? pbq1 : pbq0;
            ushort4 xr = *(const ushort4*)&xT[nn * 136 + o0];
            float v0 = acc[m][j][0] + pb.x + b2f(xr.x);
            float v1 = acc[m][j][1] + pb.y + b2f(xr.y);
            float v2 = acc[m][j][2] + pb.z + b2f(xr.z);
            float v3 = acc[m][j][3] + pb.w + b2f(xr.w);
            us4v ov = { f2b(v0), f2b(v1), f2b(v2), f2b(v3) };
            __builtin_nontemporal_store(ov, (us4v*)(obase + o0));
            s += (v0 + v1) + (v2 + v3);
            sq = fmaf(v0, v0, sq); sq = fmaf(v1, v1, sq);
            sq = fmaf(v2, v2, sq); sq = fmaf(v3, v3, sq);
        }
    }
#pragma unroll
    for (int off = 32; off > 0; off >>= 1) {
        s += __shfl_down(s, off, 64);
        sq += __shfl_down(sq, off, 64);
    }
    if (lane == 0) {
        atomicAdd(&st[0 + b], s);
        atomicAdd(&st[8 + b], sq);
    }
}

// ---------- LN2 apply, direct f32 params; stats inline from raw sums ----------
__global__ __launch_bounds__(256) void k_lnapply(const float* __restrict__ in,
                                                 const float* __restrict__ lnw,
                                                 const float* __restrict__ lnb,
                                                 const float* __restrict__ st,
                                                 float* __restrict__ out) {
    size_t i4 = (size_t)blockIdx.x * 256 + threadIdx.x;
    int b = (int)(i4 >> 20);
    size_t cn = i4 * 4 - (size_t)b * 4194304;
    float mu, rs;
    ln_stats(st, 32, b, mu, rs);
    const float4 xv = *(const float4*)(in + (size_t)b * DS + cn);
    const float4 wv = *(const float4*)(lnw + cn);
    const float4 bv = *(const float4*)(lnb + cn);
    float4 o;
    o.x = fmaf((xv.x - mu) * rs, wv.x, bv.x);
    o.y = fmaf((xv.y - mu) * rs, wv.y, bv.y);
    o.z = fmaf((xv.z - mu) * rs, wv.z, bv.z);
    o.w = fmaf((xv.w - mu) * rs, wv.w, bv.w);
    *(float4*)(out + (size_t)b * DS + cn) = o;
}

// ---------- fused LN1-apply + MLP + residual + LN2 stats, 128-n tile (R15 schedule) ----------
__global__ __launch_bounds__(256, 2) void k_mlp(const ushort* __restrict__ x1Tb,
                                                float* __restrict__ xout,
                                                const ushort* __restrict__ w1b,
                                                const float* __restrict__ b1v,
                                                const ushort* __restrict__ w2b,
                                                const float* __restrict__ b2v,
                                                const uint* __restrict__ lnwbT,
                                                float* __restrict__ st) {
    __shared__ ushort xT[128 * 128];   // swizzled, x1 = LN1(x1pre) bf16
    __shared__ ushort hT[128 * 128];   // swizzled, gelu os-slice [n][hr] bf16
    const int b = blockIdx.y;
    const int n0 = blockIdx.x * 128;
    const int t = threadIdx.x;
    const int wave = t >> 6, lane = t & 63, q = lane >> 4, r = lane & 15;
    float mu, rs;
    ln_stats(st, 0, b, mu, rs);
    {
        // 16 col-groups of 8 c x 16 rows/pass; 2 batches, 12 nt loads in flight
        const int c8 = (t & 15) * 8, rb = t >> 4;
        const ushort* xb = x1Tb + (size_t)b * DS + (size_t)n0 * 128;
        const uint*  wb = lnwbT + (size_t)n0 * 128;
#pragma unroll
        for (int gb = 0; gb < 2; ++gb) {
            s8b xv[4]; u4v wv0[4], wv1[4];
#pragma unroll
            for (int u = 0; u < 4; ++u) {
                int nn = (gb * 4 + u) * 16 + rb;
                xv[u]  = __builtin_nontemporal_load((const s8b*)(xb + (size_t)nn * 128 + c8));
                wv0[u] = __builtin_nontemporal_load((const u4v*)(wb + (size_t)nn * 128 + c8));
                wv1[u] = __builtin_nontemporal_load((const u4v*)(wb + (size_t)nn * 128 + c8 + 4));
            }
#pragma unroll
            for (int u = 0; u < 4; ++u) {
                int nn = (gb * 4 + u) * 16 + rb;
                ushort4 p0, p1;
                float xe;
                xe = b2f((ushort)xv[u][0]);
                p0.x = f2b(fmaf((xe - mu) * rs, b2f((ushort)(wv0[u].x & 0xffffu)), b2f((ushort)(wv0[u].x >> 16))));
                xe = b2f((ushort)xv[u][1]);
                p0.y = f2b(fmaf((xe - mu) * rs, b2f((ushort)(wv0[u].y & 0xffffu)), b2f((ushort)(wv0[u].y >> 16))));
                xe = b2f((ushort)xv[u][2]);
                p0.z = f2b(fmaf((xe - mu) * rs, b2f((ushort)(wv0[u].z & 0xffffu)), b2f((ushort)(wv0[u].z >> 16))));
                xe = b2f((ushort)xv[u][3]);
                p0.w = f2b(fmaf((xe - mu) * rs, b2f((ushort)(wv0[u].w & 0xffffu)), b2f((ushort)(wv0[u].w >> 16))));
                xe = b2f((ushort)xv[u][4]);
                p1.x = f2b(fmaf((xe - mu) * rs, b2f((ushort)(wv1[u].x & 0xffffu)), b2f((ushort)(wv1[u].x >> 16))));
                xe = b2f((ushort)xv[u][5]);
                p1.y = f2b(fmaf((xe - mu) * rs, b2f((ushort)(wv1[u].y & 0xffffu)), b2f((ushort)(wv1[u].y >> 16))));
                xe = b2f((ushort)xv[u][6]);
                p1.z = f2b(fmaf((xe - mu) * rs, b2f((ushort)(wv1[u].z & 0xffffu)), b2f((ushort)(wv1[u].z >> 16))));
                xe = b2f((ushort)xv[u][7]);
                p1.w = f2b(fmaf((xe - mu) * rs, b2f((ushort)(wv1[u].w & 0xffffu)), b2f((ushort)(wv1[u].w >> 16))));
                *(ushort4*)&xT[swz4(nn, c8)] = p0;
                *(ushort4*)&xT[swz4(nn, c8 + 4)] = p1;
            }
        }
    }
    const int orow = wave * 32 + r;
    // prefetch GEMM1 A-slice for os=0 (8 independent loads), overlaps barrier
    s8b a1[8];
    {
        const ushort* w1p = w1b + (size_t)orow * 128 + q * 8;
#pragma unroll
        for (int m = 0; m < 2; ++m)
#pragma unroll
            for (int kk = 0; kk < 4; ++kk)
                a1[m * 4 + kk] = *(const s8b*)(w1p + m * 16 * 128 + kk * 32);
    }
    __syncthreads();
    // acc2 initialized with b2 (bias folded into MFMA C-in)
    float4 b2q0 = *(const float4*)&b2v[wave * 32 + q * 4];
    float4 b2q1 = *(const float4*)&b2v[wave * 32 + 16 + q * 4];
    f4 acc2[2][8];
#pragma unroll
    for (int j = 0; j < 8; ++j) {
        acc2[0][j] = (f4){b2q0.x, b2q0.y, b2q0.z, b2q0.w};
        acc2[1][j] = (f4){b2q1.x, b2q1.y, b2q1.z, b2q1.w};
    }

    for (int os = 0; os < 4; ++os) {
        // ---- GEMM1: h[os-slice rows owned by wave] = W1 x1 + b1 (b1 in C-in) ----
        float4 b1q0 = *(const float4*)&b1v[os * 128 + wave * 32 + q * 4];
        float4 b1q1 = *(const float4*)&b1v[os * 128 + wave * 32 + 16 + q * 4];
        f4 acc1[2][8];
#pragma unroll
        for (int j = 0; j < 8; ++j) {
            acc1[0][j] = (f4){b1q0.x, b1q0.y, b1q0.z, b1q0.w};
            acc1[1][j] = (f4){b1q1.x, b1q1.y, b1q1.z, b1q1.w};
        }
#pragma unroll
        for (int kk = 0; kk < 4; ++kk) {
            const int c0 = kk * 32 + q * 8;
#pragma unroll
            for (int j = 0; j < 8; ++j) {
                s8b bx = *(const s8b*)&xT[swz8(j * 16 + r, c0)];
                acc1[0][j] = __builtin_amdgcn_mfma_f32_16x16x32_bf16(a1[kk],     bx, acc1[0][j], 0, 0, 0);
                acc1[1][j] = __builtin_amdgcn_mfma_f32_16x16x32_bf16(a1[4 + kk], bx, acc1[1][j], 0, 0, 0);
            }
        }
        // prefetch GEMM2 A-slice for this os (independent of hT)
        s8b a2[8];
        {
            const ushort* w2p = w2b + (size_t)orow * 512 + os * 128 + q * 8;
#pragma unroll
            for (int m = 0; m < 2; ++m)
#pragma unroll
                for (int kk = 0; kk < 4; ++kk)
                    a2[m * 4 + kk] = *(const s8b*)(w2p + m * 16 * 512 + kk * 32);
        }
        // ---- gelu -> hT (cross-wave) ----
#pragma unroll
        for (int m = 0; m < 2; ++m) {
            const int hr0 = wave * 32 + m * 16 + q * 4;
#pragma unroll
            for (int j = 0; j < 8; ++j) {
                ushort4 pk;
                pk.x = f2b(gelu_f(acc1[m][j][0]));
                pk.y = f2b(gelu_f(acc1[m][j][1]));
                pk.z = f2b(gelu_f(acc1[m][j][2]));
                pk.w = f2b(gelu_f(acc1[m][j][3]));
                *(ushort4*)&hT[swz4(j * 16 + r, hr0)] = pk;
            }
        }
        __syncthreads();   // hT complete across waves
        // ---- GEMM2: acc2 += W2[:, os-slice] h ----
#pragma unroll
        for (int kk = 0; kk < 4; ++kk) {
            const int c0 = kk * 32 + q * 8;
#pragma unroll
            for (int j = 0; j < 8; ++j) {
                s8b hx = *(const s8b*)&hT[swz8(j * 16 + r, c0)];
                acc2[0][j] = __builtin_amdgcn_mfma_f32_16x16x32_bf16(a2[kk],     hx, acc2[0][j], 0, 0, 0);
                acc2[1][j] = __builtin_amdgcn_mfma_f32_16x16x32_bf16(a2[4 + kk], hx, acc2[1][j], 0, 0, 0);
            }
        }
        // prefetch next os's GEMM1 A-slice (overlaps barrier drain)
        if (os < 3) {
            const ushort* w1p = w1b + (size_t)((os + 1) * 128 + orow) * 128 + q * 8;
#pragma unroll
            for (int m = 0; m < 2; ++m)
#pragma unroll
                for (int kk = 0; kk < 4; ++kk)
                    a1[m * 4 + kk] = *(const s8b*)(w1p + m * 16 * 128 + kk * 32);
        }
        __syncthreads();   // hT consumed; safe to overwrite next os
    }
    // ---- epilogue: residual (b2 already in acc2), normal strided store, LN2 stats ----
    float s = 0.f, sq = 0.f;
#pragma unroll
    for (int m = 0; m < 2; ++m) {
        const int o0 = wave * 32 + m * 16 + q * 4;
#pragma unroll
        for (int j = 0; j < 8; ++j) {
            const int nn = j * 16 + r;
            ushort4 xr = *(const ushort4*)&xT[swz4(nn, o0)];
            float v0 = acc2[m][j][0] + b2f(xr.x);
            float v1 = acc2[m][j][1] + b2f(xr.y);
            float v2 = acc2[m][j][2] + b2f(xr.z);
            float v3 = acc2[m][j][3] + b2f(xr.w);
            float* op = xout + (size_t)b * DS + n0 + nn;
            op[(size_t)(o0 + 0) * N_SP] = v0;
            op[(size_t)(o0 + 1) * N_SP] = v1;
            op[(size_t)(o0 + 2) * N_SP] = v2;
            op[(size_t)(o0 + 3) * N_SP] = v3;
            s += (v0 + v1) + (v2 + v3);
            sq = fmaf(v0, v0, sq); sq = fmaf(v1, v1, sq);
            sq = fmaf(v2, v2, sq); sq = fmaf(v3, v3, sq);
        }
    }
#pragma unroll
    for (int off = 32; off > 0; off >>= 1) {
        s += __shfl_down(s, off, 64);
        sq += __shfl_down(sq, off, 64);
    }
    if (lane == 0) {
        atomicAdd(&st[32 + b], s);
        atomicAdd(&st[40 + b], sq);
    }
}

extern "C" void kernel_launch(void* const* d_in, const int* in_sizes, int n_in,
                              void* d_out, int out_size, void* d_ws, size_t ws_size,
                              hipStream_t stream) {
    const float* x      = (const float*)d_in[0];
    const float* qkv_w  = (const float*)d_in[1];
    const float* proj_w = (const float*)d_in[2];
    const float* proj_b = (const float*)d_in[3];
    const float* ln1_w  = (const float*)d_in[4];
    const float* ln1_b  = (const float*)d_in[5];
    const float* ln2_w  = (const float*)d_in[6];
    const float* ln2_b  = (const float*)d_in[7];
    const float* mlp_w1 = (const float*)d_in[8];
    const float* mlp_b1 = (const float*)d_in[9];
    const float* mlp_w2 = (const float*)d_in[10];
    const float* mlp_b2 = (const float*)d_in[11];
    float* out = (float*)d_out;

    char* wsb = (char*)d_ws;
    // small persistent region
    float*  st    = (float*)wsb;                      // 256 B
    float*  attn  = (float*)(wsb + 256);              // 65,536
    float*  PT    = (float*)(wsb + 65792);            // 65,536
    ushort* Mbb   = (ushort*)(wsb + 131328);          // 262,144
    ushort* w1b   = (ushort*)(wsb + 393472);          // 131,072
    ushort* w2b   = (ushort*)(wsb + 524544);          // 131,072
    float*  G     = (float*)(wsb + 655616);           // 524,288
    uint*   lnwbT = (uint*)(wsb + 1179904);           // 16,777,216
    // big dual-use region (stream-ordered lifetimes):
    //   Gpart (33.5MB, dead after k_greduce) -> x1Tb bf16 (67MB, dead after k_mlp)
    float*  Gpart = (float*)(wsb + 18874368);         // 33,554,432
    ushort* x1Tb  = (ushort*)(wsb + 18874368);        // 67,108,864

    hipMemsetAsync(st, 0, 64 * sizeof(float), stream);

    k_prep<<<1088, 256, 0, stream>>>(proj_w, PT, mlp_w1, w1b, mlp_w2, w2b,
                                     ln1_w, ln1_b, lnwbT);

    k_cov<<<dim3(64, 8), 256, 0, stream>>>(x, Gpart);
    k_greduce<<<512, 256, 0, stream>>>(Gpart, G);
    k_gram_small<<<64, 256, 0, stream>>>(G, qkv_w, attn);
    k_mfold<<<dim3(4, 8), 256, 0, stream>>>(attn, qkv_w, PT, Mbb);

    k_attnproj<<<dim3(256, 8), 256, 0, stream>>>(x, Mbb, proj_b, x1Tb, st);
    k_mlp<<<dim3(256, 8), 256, 0, stream>>>(x1Tb, out, w1b, mlp_b1, w2b, mlp_b2,
                                            lnwbT, st);
    k_lnapply<<<32768, 256, 0, stream>>>(out, ln2_w, ln2_b, st, out);
}